// Round 10
// baseline (447.320 us; speedup 1.0000x reference)
//
#include <hip/hip_runtime.h>
#include <math.h>

// Problem constants
#define B_     8
#define S_     4
#define H_     50
#define NH_    200
#define EHH_   400
#define L_     2
#define HID_   128
#define FDIM_  79          // 44 + 20 + 15
#define EDIM_  161         // 2*FDIM + 3
#define NN_    250         // H + NH
#define NE_    10400       // EHH + H*NH
#define BS_    32          // B*S
#define TOTE_  (BS_*NE_)   // 332800
#define FS_    80          // feat row stride
#define TE_    64          // edges per block in edge kernel
#define MSTR_  136         // s_m stride in bf16 (128 + 8)
#define NDIM_  207         // FDIM + HID

// Workspace layout (float offsets)
#define OFF_FEATH  0         // BS*H*80 = 128000
#define OFF_X      128000    // BS*NN*4 = 32000
#define OFF_X0H    160000    // BS*H*4  = 6400
#define OFF_EROW   166400    // 83200 (int)
#define OFF_ECOL   249600    // 83200 (int)
#define OFF_EMASK  332800    // 83200
#define OFF_EBOND  416000    // 83200
#define OFF_AGG0   499200    // aggx0(6400) + aggm0(204800) = 211200
#define OFF_AGG1   710400    // 211200
#define OFF_HIW1   921600    // fp32 1600*128 (b1 + t*w160 folded in)
#define OFF_HJW1   1126400   // fp32 4800*128: [0,1600) h cur | [1600,3200) hv l0 | [3200,4800) hv l1
#define OFF_WP     1740800   // 65536 ushort
#define AGGSTRIDE_ 211200

typedef __attribute__((ext_vector_type(8))) short short8;
typedef __attribute__((ext_vector_type(4))) float f32x4;

__device__ __forceinline__ float silu_(float v) {
    return v * __builtin_amdgcn_rcpf(1.0f + __expf(-v));
}
__device__ __forceinline__ unsigned short f2bf(float f) {
    unsigned int u = __float_as_uint(f);
    unsigned int r = (u + 0x7fffu + ((u >> 16) & 1u)) >> 16;
    return (unsigned short)r;
}
__device__ __forceinline__ float bf2f(unsigned short v) {
    return __uint_as_float(((unsigned int)v) << 16);
}

// ================= fused setup =================
#define HV_BLKS_    1600   // heavy hjW1 both layers: 409600
#define PACK_BLKS_  256    // 65536
#define EDGE_BLKS_  325    // grid edges of 83200 (skip e<400)
#define SORT_BLKS_  8      // counting-sort hh edges by row, per b
#define HROW_BLKS_  200    // 400*128
#define FEAT_BLKS_  125    // 400*80
#define ZERO_BLKS_  207    // 52800 float4
#define XI_BLKS_    32     // 8000
#define SETUP_BLKS_ (HV_BLKS_ + PACK_BLKS_ + EDGE_BLKS_ + SORT_BLKS_ + HROW_BLKS_ + FEAT_BLKS_ + ZERO_BLKS_ + XI_BLKS_)

__global__ __launch_bounds__(256) void k_setup(
    const float* __restrict__ x_h, const float* __restrict__ x_hv,
    const int* __restrict__ bound,
    const int* __restrict__ ehh, const float* __restrict__ em_hh,
    const float* __restrict__ em_hv, const float* __restrict__ bond,
    const float* __restrict__ W1, const float* __restrict__ b1,
    const float* __restrict__ t_in,
    const float* __restrict__ W2, const float* __restrict__ Wc1,
    const int* __restrict__ lab_h, const int* __restrict__ pos_h,
    const int* __restrict__ lab_hv, const int* __restrict__ pos_hv,
    const int* __restrict__ pep,
    float* __restrict__ feat_h,
    float* __restrict__ x, float* __restrict__ x0h,
    int* __restrict__ erow, int* __restrict__ ecol,
    float* __restrict__ emk, float* __restrict__ ebd,
    float* __restrict__ hiW1, float* __restrict__ hjW1,
    float* __restrict__ agg0,
    unsigned short* __restrict__ Wp)
{
    int blk = blockIdx.x, t = threadIdx.x;
    if (blk < HV_BLKS_) {
        int g = blk*256 + t;                 // [0, 409600)
        int l = g / 204800;
        int r = g - l*204800;
        int node = r >> 7, col = r & 127;    // node = b*NH + nh
        int b = node / NH_;
        int label = lab_hv[node], pos = pos_hv[node];
        int aa = pep[b*15 + pos - 1];
        const float* W1l = W1 + l*EDIM_*HID_;
        float hj = W1l[(FDIM_ + label)*HID_ + col]
                 + W1l[(FDIM_ + 44 + aa)*HID_ + col]
                 + W1l[(FDIM_ + 64 + pos - 1)*HID_ + col];
        hjW1[(size_t)(1600 + l*1600 + node)*HID_ + col] = hj;
        return;
    }
    blk -= HV_BLKS_;
    if (blk < PACK_BLKS_) {
        int g = blk*256 + t;
        int idx = g & 16383;
        int lm  = g >> 14;
        int l = lm >> 1, mat = lm & 1;
        int j = idx & 7, q = (idx >> 3) & 3, n = (idx >> 5) & 127, kc = idx >> 12;
        int k = kc*32 + q*8 + j;
        const float* W = (mat == 0 ? W2 : Wc1) + l*HID_*HID_;
        Wp[g] = f2bf(W[k*HID_ + n]);
        return;
    }
    blk -= PACK_BLKS_;
    if (blk < EDGE_BLKS_) {
        int g = blk*256 + t;                  // [0, 83200)
        int b = g / NE_, e = g % NE_;
        if (e < EHH_) return;                 // hh edges handled by sort phase
        int k = e - EHH_;
        int r = k / NH_; int cc = k % NH_; int c = H_ + cc;
        erow[g] = r; ecol[g] = c;
        emk[g] = em_hv[(b*H_ + r)*NH_ + cc];
        ebd[g] = bond [(b*H_ + r)*NH_ + cc];
        return;
    }
    blk -= EDGE_BLKS_;
    if (blk < SORT_BLKS_) {
        // counting-sort the 400 hh edges of batch b by row -> long runs for agg
        int b = blk;
        __shared__ int scnt[64];
        __shared__ int srow[EHH_], scol[EHH_];
        __shared__ float sem[EHH_];
        if (t < 64) scnt[t] = 0;
        __syncthreads();
        for (int e = t; e < EHH_; e += 256) {
            int r = ehh[(b*EHH_ + e)*2 + 0];
            srow[e] = r;
            scol[e] = ehh[(b*EHH_ + e)*2 + 1];
            sem[e]  = em_hh[b*EHH_ + e];
            atomicAdd(&scnt[r], 1);
        }
        __syncthreads();
        if (t == 0) {
            int acc = 0;
            for (int i = 0; i < H_; ++i) { int v = scnt[i]; scnt[i] = acc; acc += v; }
        }
        __syncthreads();
        for (int e = t; e < EHH_; e += 256) {
            int r = srow[e];
            int pos = atomicAdd(&scnt[r], 1);
            int g = b*NE_ + pos;
            erow[g] = r; ecol[g] = scol[e]; emk[g] = sem[e]; ebd[g] = 0.0f;
        }
        return;
    }
    blk -= SORT_BLKS_;
    if (blk < HROW_BLKS_) {
        // h-node layer-0 projections; fold b1 and t*w160 into hiW1
        int g = blk*256 + t;                 // [0, 51200)
        int node = g >> 7, col = g & 127;    // node = b*H + h
        int b = node / H_;
        int label = lab_h[node], pos = pos_h[node];
        int aa = pep[b*15 + pos - 1];
        const float* W1l = W1;               // layer 0
        float hi = W1l[label*HID_ + col]
                 + W1l[(44 + aa)*HID_ + col]
                 + W1l[(64 + pos - 1)*HID_ + col]
                 + b1[col]
                 + t_in[b] * W1l[160*HID_ + col];
        float hj = W1l[(FDIM_ + label)*HID_ + col]
                 + W1l[(FDIM_ + 44 + aa)*HID_ + col]
                 + W1l[(FDIM_ + 64 + pos - 1)*HID_ + col];
        int h = node % H_;
        #pragma unroll
        for (int s = 0; s < S_; ++s) {
            int row = (b*S_ + s)*H_ + h;
            hiW1[(size_t)row*HID_ + col] = hi;
            hjW1[(size_t)row*HID_ + col] = hj;
        }
        return;
    }
    blk -= HROW_BLKS_;
    if (blk < FEAT_BLKS_) {
        int g = blk*256 + t;                 // [0, 32000)
        int node = g / FS_, f = g % FS_;     // node = b*H + h
        int b = node / H_, h = node % H_;
        int label = lab_h[node], pos = pos_h[node];
        int aa = pep[b*15 + pos - 1];
        float v = 0.f;
        if (f < 44)      v = (f == label)          ? 1.0f : 0.0f;
        else if (f < 64) v = ((f - 44) == aa)      ? 1.0f : 0.0f;
        else if (f < 79) v = ((f - 64) == pos - 1) ? 1.0f : 0.0f;
        #pragma unroll
        for (int s = 0; s < S_; ++s)
            feat_h[((b*S_ + s)*H_ + h)*FS_ + f] = v;
        return;
    }
    blk -= FEAT_BLKS_;
    if (blk < ZERO_BLKS_) {
        int idx = blk*256 + t;
        if (idx < 52800) ((float4*)agg0)[idx] = make_float4(0.f, 0.f, 0.f, 0.f);
        return;
    }
    blk -= ZERO_BLKS_;
    {
        int g = blk*256 + t;
        if (g >= BS_*NN_) return;
        int bs = g / NN_, n = g % NN_;
        int b = bs / S_;
        if (n < H_) {
            int ba = bound[b*H_ + n];
            for (int d = 0; d < 3; ++d) {
                float v = x_h[(bs*H_ + n)*3 + d] + x_hv[(b*NH_ + ba)*3 + d];
                x[g*4 + d] = v;
                x0h[(bs*H_ + n)*4 + d] = v;
            }
        } else {
            int nh = n - H_;
            for (int d = 0; d < 3; ++d) x[g*4 + d] = x_hv[(b*NH_ + nh)*3 + d];
        }
    }
}

// ============ per-layer: fused MFMA edge MLP + segment aggregation ============
// __launch_bounds__(256,6): R9 showed Occupancy=39% with a (256,4) cap while
// VGPR=56 (budget 84 at 6 wv/SIMD) and LDS 24064*6=144K<=160K both allow 6
// blocks/CU. Latency-bound kernel (VALUBusy 34%, MfmaUtil 6.6%, HBM 1.4%)
// -> more resident waves hide the gather->LDS->MFMA chains.
__global__ __launch_bounds__(256, 6) void k_edge_mlp(
    const float* __restrict__ x, const float* __restrict__ hiW1,
    const float* __restrict__ hjW1,
    const int* __restrict__ erow, const int* __restrict__ ecol,
    const float* __restrict__ emk, const float* __restrict__ ebd,
    const float* __restrict__ W1,
    const float* __restrict__ b2, const float* __restrict__ bc1,
    const float* __restrict__ Wc2,
    const unsigned short* __restrict__ Wp, int l,
    float* __restrict__ aggx, float* __restrict__ aggm)
{
    __shared__ unsigned short s_m[TE_][MSTR_];   // 17408 B
    __shared__ float s_partT[16][68];            // 4352 B
    __shared__ float s_diff[TE_][4];
    __shared__ float s_db  [TE_][2];             // dist, bond
    __shared__ float s_emk [TE_];
    __shared__ int   s_ii  [TE_];                // bs*H + row
    __shared__ int   s_jj  [TE_];                // hjW1 row index

    const int t = threadIdx.x;
    const int lane = t & 63, w = t >> 6;
    const int l15 = lane & 15, q = lane >> 4;

    // ---- setup: per-edge scalars ----
    if (t < TE_) {
        int ge = blockIdx.x*TE_ + t;
        int bs = ge / NE_;
        int e  = ge - bs*NE_;
        int b  = bs / S_;
        int row = erow[b*NE_ + e], col = ecol[b*NE_ + e];
        s_ii[t] = bs*H_ + row;
        s_jj[t] = (col < H_) ? (bs*H_ + col) : (1600 + l*1600 + b*NH_ + (col - H_));
        float dx0 = x[(bs*NN_ + row)*4 + 0] - x[(bs*NN_ + col)*4 + 0];
        float dx1 = x[(bs*NN_ + row)*4 + 1] - x[(bs*NN_ + col)*4 + 1];
        float dx2 = x[(bs*NN_ + row)*4 + 2] - x[(bs*NN_ + col)*4 + 2];
        s_diff[t][0] = dx0; s_diff[t][1] = dx1; s_diff[t][2] = dx2;
        s_db[t][0] = sqrtf(dx0*dx0 + dx1*dx1 + dx2*dx2);
        s_db[t][1] = ebd[b*NE_ + e];
        s_emk[t]   = emk[b*NE_ + e];
    }
    __syncthreads();

    const int mrow = w*16 + l15;   // this lane's A-row (edge)

    // ---- stage 1 (register-direct): b1,t*w160 pre-folded into hiW1 ----
    short8 afrag[4];
    {
        const float* W1l = W1 + l*EDIM_*HID_;
        int ri = s_ii[mrow], rj = s_jj[mrow];
        float dist = s_db[mrow][0], bond = s_db[mrow][1];
        const float* pi = hiW1 + (size_t)ri*HID_ + q*8;
        const float* pj = hjW1 + (size_t)rj*HID_ + q*8;
        #pragma unroll
        for (int kc = 0; kc < 4; ++kc) {
            int k0 = kc*32 + q*8;
            float4 a0 = *(const float4*)(pi + kc*32);
            float4 a1 = *(const float4*)(pi + kc*32 + 4);
            float4 c0 = *(const float4*)(pj + kc*32);
            float4 c1 = *(const float4*)(pj + kc*32 + 4);
            float4 wa0 = *(const float4*)(W1l + 158*HID_ + k0);
            float4 wa1 = *(const float4*)(W1l + 158*HID_ + k0 + 4);
            float4 wb0 = *(const float4*)(W1l + 159*HID_ + k0);
            float4 wb1 = *(const float4*)(W1l + 159*HID_ + k0 + 4);
            short8 fr;
            fr[0] = (short)f2bf(silu_(a0.x + c0.x + dist*wa0.x + bond*wb0.x));
            fr[1] = (short)f2bf(silu_(a0.y + c0.y + dist*wa0.y + bond*wb0.y));
            fr[2] = (short)f2bf(silu_(a0.z + c0.z + dist*wa0.z + bond*wb0.z));
            fr[3] = (short)f2bf(silu_(a0.w + c0.w + dist*wa0.w + bond*wb0.w));
            fr[4] = (short)f2bf(silu_(a1.x + c1.x + dist*wa1.x + bond*wb1.x));
            fr[5] = (short)f2bf(silu_(a1.y + c1.y + dist*wa1.y + bond*wb1.y));
            fr[6] = (short)f2bf(silu_(a1.z + c1.z + dist*wa1.z + bond*wb1.z));
            fr[7] = (short)f2bf(silu_(a1.w + c1.w + dist*wa1.w + bond*wb1.w));
            afrag[kc] = fr;
        }
    }

    // ---- stage 2: m = silu(m1 @ W2 + b2) * emask  (bias in acc init) ----
    {
        const unsigned short* Wp2 = Wp + (size_t)(l*2 + 0)*16384;
        const float* b2l = b2 + l*HID_;
        float em4[4];
        #pragma unroll
        for (int r = 0; r < 4; ++r) em4[r] = s_emk[w*16 + q*4 + r];
        #pragma unroll
        for (int nt = 0; nt < 8; ++nt) {
            int colj = nt*16 + l15;
            float bias = b2l[colj];
            f32x4 c = {bias, bias, bias, bias};
            #pragma unroll
            for (int kc = 0; kc < 4; ++kc) {
                short8 bfrag = *(const short8*)&Wp2[((kc*128 + nt*16 + l15)*4 + q)*8];
                c = __builtin_amdgcn_mfma_f32_16x16x32_bf16(afrag[kc], bfrag, c, 0, 0, 0);
            }
            #pragma unroll
            for (int r = 0; r < 4; ++r)
                s_m[w*16 + q*4 + r][colj] = f2bf(silu_(c[r]) * em4[r]);
        }
    }
    __builtin_amdgcn_wave_barrier();   // wave-private rows: ds_write before ds_read

    // ---- stage 3: cw = silu(m @ Wc1 + bc1) @ Wc2 ----
    {
        short8 af2[4];
        #pragma unroll
        for (int kc = 0; kc < 4; ++kc)
            af2[kc] = *(const short8*)&s_m[mrow][kc*32 + q*8];
        const unsigned short* Wp3 = Wp + (size_t)(l*2 + 1)*16384;
        const float* bc1l = bc1 + l*HID_;
        const float* wc2l = Wc2 + l*HID_;
        float p[4] = {0.f, 0.f, 0.f, 0.f};
        #pragma unroll
        for (int nt = 0; nt < 8; ++nt) {
            int colj = nt*16 + l15;
            float bias = bc1l[colj];
            f32x4 c = {bias, bias, bias, bias};
            #pragma unroll
            for (int kc = 0; kc < 4; ++kc) {
                short8 bfrag = *(const short8*)&Wp3[((kc*128 + nt*16 + l15)*4 + q)*8];
                c = __builtin_amdgcn_mfma_f32_16x16x32_bf16(af2[kc], bfrag, c, 0, 0, 0);
            }
            float wcv = wc2l[colj];
            #pragma unroll
            for (int r = 0; r < 4; ++r)
                p[r] += silu_(c[r]) * wcv;
        }
        *(float4*)&s_partT[l15][w*16 + q*4] = make_float4(p[0], p[1], p[2], p[3]);
    }
    __syncthreads();

    // ---- aggregation (R4 layout — measured clean: 0.33M conflicts, 4.3 MB writes):
    // wave 0: cw reduce + aggx via shuffle; waves 1,2: aggm full 64-edge scans ----
    if (t < TE_) {
        float cwv = 0.f;
        #pragma unroll
        for (int c = 0; c < 16; ++c) cwv += s_partT[c][t];
        float run = 0.f; int ct = s_ii[0];
        int d = lane & 3;                       // lanes 0..2 meaningful
        for (int i2 = 0; i2 < TE_; ++i2) {
            float cwi = __shfl(cwv, i2, 64);
            int tg = s_ii[i2];
            if (tg != ct) {
                if (lane < 3) atomicAdd(&aggx[(size_t)ct*4 + d], run);
                run = 0.f; ct = tg;
            }
            run += s_diff[i2][d] * cwi;
        }
        if (lane < 3) atomicAdd(&aggx[(size_t)ct*4 + d], run);
    } else if (t < TE_ + HID_) {
        int j = t - TE_;
        float run = 0.f; int ct = s_ii[0];
        for (int i2 = 0; i2 < TE_; ++i2) {
            int tg = s_ii[i2];
            if (tg != ct) {
                atomicAdd(&aggm[(size_t)ct*HID_ + j], run);
                run = 0.f; ct = tg;
            }
            run += bf2f(s_m[i2][j]);
        }
        atomicAdd(&aggm[(size_t)ct*HID_ + j], run);
    }
}

// ====== per-layer: node update (8 nodes/block) + next-layer W1 (folded) + out ======
__global__ __launch_bounds__(128) void k_update(
    float* __restrict__ feat_h, float* __restrict__ x,
    const float* __restrict__ aggm, const float* __restrict__ aggx,
    const float* __restrict__ Wn1, const float* __restrict__ bn1,
    const float* __restrict__ Wn2, const float* __restrict__ bn2, int l,
    const float* __restrict__ W1, const float* __restrict__ b1,
    const float* __restrict__ t_in,
    float* __restrict__ hiW1, float* __restrict__ hjW1,
    float* __restrict__ zbase, int do_w1,
    const float* __restrict__ x0h, const float* __restrict__ amask,
    float* __restrict__ out)
{
    if (blockIdx.x >= 200) {
        int z = blockIdx.x - 200;
        for (int idx = z*128 + threadIdx.x; idx < 52800; idx += 207*128)
            ((float4*)zbase)[idx] = make_float4(0.f, 0.f, 0.f, 0.f);
        return;
    }
    __shared__ float s_in[8][NDIM_ + 1];
    __shared__ float s_u[8][HID_ + 1];
    int node0 = blockIdx.x * 8;            // bs*H + h
    int t = threadIdx.x;
    for (int idx = t; idx < 8*(NDIM_ + 1); idx += 128) {
        int g = idx / (NDIM_ + 1), k = idx % (NDIM_ + 1);
        float v = 0.f;
        if (k < FDIM_)      v = feat_h[(node0 + g)*FS_ + k];
        else if (k < NDIM_) v = aggm[(size_t)(node0 + g)*HID_ + (k - FDIM_)];
        s_in[g][k] = v;
    }
    __syncthreads();
    const float* Wn1l = Wn1 + l*NDIM_*HID_;
    float acc[8];
    float bv = bn1[l*HID_ + t];
    #pragma unroll
    for (int g = 0; g < 8; ++g) acc[g] = bv;
    for (int k = 0; k < NDIM_; ++k) {
        float wv = Wn1l[k*HID_ + t];
        #pragma unroll
        for (int g = 0; g < 8; ++g) acc[g] += s_in[g][k] * wv;
    }
    #pragma unroll
    for (int g = 0; g < 8; ++g) s_u[g][t] = silu_(acc[g]);
    __syncthreads();
    if (t < FDIM_) {
        const float* Wn2l = Wn2 + l*HID_*FDIM_;
        float acc2[8];
        float b2v = bn2[l*FDIM_ + t];
        #pragma unroll
        for (int g = 0; g < 8; ++g) acc2[g] = b2v;
        for (int k = 0; k < HID_; ++k) {
            float wv = Wn2l[k*FDIM_ + t];
            #pragma unroll
            for (int g = 0; g < 8; ++g) acc2[g] += s_u[g][k] * wv;
        }
        #pragma unroll
        for (int g = 0; g < 8; ++g) {
            float nf = s_in[g][t] + acc2[g];
            feat_h[(node0 + g)*FS_ + t] = nf;
            s_in[g][t] = nf;
        }
    } else if (t >= 96 && t < 120) {
        int idx = t - 96, g = idx / 3, d = idx % 3;
        int node = node0 + g;
        int bs = node / H_, h = node % H_;
        float xv = x[(bs*NN_ + h)*4 + d] + aggx[node*4 + d];
        x[(bs*NN_ + h)*4 + d] = xv;
        if (!do_w1) {
            int b = bs / S_;
            out[node*3 + d] = (xv - x0h[node*4 + d]) * amask[b*H_ + h];
        }
    }
    if (!do_w1) return;
    __syncthreads();
    // ---- next-layer W1 projections (fold b1 + t*w160 into hiW1) ----
    {
        const float* W1n = W1 + (l + 1)*EDIM_*HID_;
        float w160 = W1n[160*HID_ + t];
        float b1v  = b1[(l + 1)*HID_ + t];
        float hia[8], hja[8];
        #pragma unroll
        for (int g = 0; g < 8; ++g) { hia[g] = 0.f; hja[g] = 0.f; }
        for (int f = 0; f < FDIM_; ++f) {
            float wi = W1n[f*HID_ + t];
            float wj = W1n[(FDIM_ + f)*HID_ + t];
            #pragma unroll
            for (int g = 0; g < 8; ++g) {
                float v = s_in[g][f];
                hia[g] += v * wi;
                hja[g] += v * wj;
            }
        }
        #pragma unroll
        for (int g = 0; g < 8; ++g) {
            int node = node0 + g;
            int b = (node / H_) / S_;
            hiW1[(size_t)node*HID_ + t] = hia[g] + b1v + t_in[b]*w160;
            hjW1[(size_t)node*HID_ + t] = hja[g];
        }
    }
}

// ---------------- launch ----------------
extern "C" void kernel_launch(void* const* d_in, const int* in_sizes, int n_in,
                              void* d_out, int out_size, void* d_ws, size_t ws_size,
                              hipStream_t stream)
{
    const float* t_in  = (const float*)d_in[0];
    const float* x_h   = (const float*)d_in[1];
    const float* x_hv  = (const float*)d_in[2];
    const float* bond  = (const float*)d_in[3];
    const float* em_hv = (const float*)d_in[4];
    const float* em_hh = (const float*)d_in[5];
    const float* amask = (const float*)d_in[6];
    const float* W1    = (const float*)d_in[7];
    const float* b1    = (const float*)d_in[8];
    const float* W2    = (const float*)d_in[9];
    const float* b2    = (const float*)d_in[10];
    const float* Wc1   = (const float*)d_in[11];
    const float* bc1   = (const float*)d_in[12];
    const float* Wc2   = (const float*)d_in[13];
    const float* Wn1   = (const float*)d_in[14];
    const float* bn1   = (const float*)d_in[15];
    const float* Wn2   = (const float*)d_in[16];
    const float* bn2   = (const float*)d_in[17];
    const int* pep     = (const int*)d_in[18];
    const int* lab_hv  = (const int*)d_in[19];
    const int* lab_h   = (const int*)d_in[20];
    const int* pos_hv  = (const int*)d_in[21];
    const int* pos_h   = (const int*)d_in[22];
    const int* ehh     = (const int*)d_in[23];
    const int* bound   = (const int*)d_in[24];

    float* ws     = (float*)d_ws;
    float* feat_h = ws + OFF_FEATH;
    float* x      = ws + OFF_X;
    float* x0h    = ws + OFF_X0H;
    int*   erow   = (int*)(ws + OFF_EROW);
    int*   ecol   = (int*)(ws + OFF_ECOL);
    float* emk    = ws + OFF_EMASK;
    float* ebd    = ws + OFF_EBOND;
    float* hiW1   = ws + OFF_HIW1;
    float* hjW1   = ws + OFF_HJW1;
    unsigned short* Wp = (unsigned short*)(ws + OFF_WP);

    hipLaunchKernelGGL(k_setup, dim3(SETUP_BLKS_), dim3(256), 0, stream,
                       x_h, x_hv, bound, ehh, em_hh, em_hv, bond,
                       W1, b1, t_in, W2, Wc1,
                       lab_h, pos_h, lab_hv, pos_hv, pep,
                       feat_h, x, x0h, erow, ecol, emk, ebd,
                       hiW1, hjW1, ws + OFF_AGG0, Wp);

    for (int l = 0; l < L_; ++l) {
        float* aggx_l = ws + OFF_AGG0 + (size_t)l*AGGSTRIDE_;
        float* aggm_l = aggx_l + 6400;
        hipLaunchKernelGGL(k_edge_mlp, dim3(TOTE_/TE_), dim3(256), 0, stream,
                           x, hiW1, hjW1, erow, ecol, emk, ebd,
                           W1, b2, bc1, Wc2, Wp, l, aggx_l, aggm_l);
        int do_w1 = (l == 0);
        float* zbase = ws + OFF_AGG0 + (size_t)(l + 1)*AGGSTRIDE_;
        hipLaunchKernelGGL(k_update, dim3(do_w1 ? 407 : 200), dim3(128), 0, stream,
                           feat_h, x, aggm_l, aggx_l, Wn1, bn1, Wn2, bn2, l,
                           W1, b1, t_in, hiW1, hjW1,
                           do_w1 ? zbase : (ws + OFF_AGG0), do_w1,
                           x0h, amask, (float*)d_out);
    }
}

// Round 11
// 440.086 us; speedup vs baseline: 1.0164x; 1.0164x over previous
//
#include <hip/hip_runtime.h>
#include <math.h>

// Problem constants
#define B_     8
#define S_     4
#define H_     50
#define NH_    200
#define EHH_   400
#define L_     2
#define HID_   128
#define FDIM_  79          // 44 + 20 + 15
#define EDIM_  161         // 2*FDIM + 3
#define NN_    250         // H + NH
#define NE_    10400       // EHH + H*NH
#define BS_    32          // B*S
#define TOTE_  (BS_*NE_)   // 332800
#define FS_    80          // feat row stride
#define TE_    64          // edges per block in edge kernel
#define MSTR_  136         // s_m stride in bf16 (128 + 8)
#define NDIM_  207         // FDIM + HID

// Workspace layout (float offsets)
#define OFF_FEATH  0         // BS*H*80 = 128000
#define OFF_X      128000    // BS*NN*4 = 32000
#define OFF_X0H    160000    // BS*H*4  = 6400
#define OFF_EROW   166400    // 83200 (int)
#define OFF_ECOL   249600    // 83200 (int)
#define OFF_EMASK  332800    // 83200
#define OFF_EBOND  416000    // 83200
#define OFF_AGG0   499200    // aggx0(6400) + aggm0(204800) = 211200
#define OFF_AGG1   710400    // 211200
#define OFF_HIW1   921600    // fp32 1600*128 (b1 + t*w160 folded in)
#define OFF_HJW1   1126400   // fp32 4800*128: [0,1600) h cur | [1600,3200) hv l0 | [3200,4800) hv l1
#define OFF_WP     1740800   // 65536 ushort
#define AGGSTRIDE_ 211200

typedef __attribute__((ext_vector_type(8))) short short8;
typedef __attribute__((ext_vector_type(4))) float f32x4;

__device__ __forceinline__ float silu_(float v) {
    return v * __builtin_amdgcn_rcpf(1.0f + __expf(-v));
}
__device__ __forceinline__ unsigned short f2bf(float f) {
    unsigned int u = __float_as_uint(f);
    unsigned int r = (u + 0x7fffu + ((u >> 16) & 1u)) >> 16;
    return (unsigned short)r;
}
__device__ __forceinline__ float bf2f(unsigned short v) {
    return __uint_as_float(((unsigned int)v) << 16);
}

// ================= fused setup =================
#define HV_BLKS_    1600   // heavy hjW1 both layers: 409600
#define PACK_BLKS_  256    // 65536
#define EDGE_BLKS_  325    // grid edges of 83200 (skip e<400)
#define SORT_BLKS_  8      // counting-sort hh edges by row, per b
#define HROW_BLKS_  200    // 400*128
#define FEAT_BLKS_  125    // 400*80
#define ZERO_BLKS_  207    // 52800 float4
#define XI_BLKS_    32     // 8000
#define SETUP_BLKS_ (HV_BLKS_ + PACK_BLKS_ + EDGE_BLKS_ + SORT_BLKS_ + HROW_BLKS_ + FEAT_BLKS_ + ZERO_BLKS_ + XI_BLKS_)

__global__ __launch_bounds__(256) void k_setup(
    const float* __restrict__ x_h, const float* __restrict__ x_hv,
    const int* __restrict__ bound,
    const int* __restrict__ ehh, const float* __restrict__ em_hh,
    const float* __restrict__ em_hv, const float* __restrict__ bond,
    const float* __restrict__ W1, const float* __restrict__ b1,
    const float* __restrict__ t_in,
    const float* __restrict__ W2, const float* __restrict__ Wc1,
    const int* __restrict__ lab_h, const int* __restrict__ pos_h,
    const int* __restrict__ lab_hv, const int* __restrict__ pos_hv,
    const int* __restrict__ pep,
    float* __restrict__ feat_h,
    float* __restrict__ x, float* __restrict__ x0h,
    int* __restrict__ erow, int* __restrict__ ecol,
    float* __restrict__ emk, float* __restrict__ ebd,
    float* __restrict__ hiW1, float* __restrict__ hjW1,
    float* __restrict__ agg0,
    unsigned short* __restrict__ Wp)
{
    int blk = blockIdx.x, t = threadIdx.x;
    if (blk < HV_BLKS_) {
        int g = blk*256 + t;                 // [0, 409600)
        int l = g / 204800;
        int r = g - l*204800;
        int node = r >> 7, col = r & 127;    // node = b*NH + nh
        int b = node / NH_;
        int label = lab_hv[node], pos = pos_hv[node];
        int aa = pep[b*15 + pos - 1];
        const float* W1l = W1 + l*EDIM_*HID_;
        float hj = W1l[(FDIM_ + label)*HID_ + col]
                 + W1l[(FDIM_ + 44 + aa)*HID_ + col]
                 + W1l[(FDIM_ + 64 + pos - 1)*HID_ + col];
        hjW1[(size_t)(1600 + l*1600 + node)*HID_ + col] = hj;
        return;
    }
    blk -= HV_BLKS_;
    if (blk < PACK_BLKS_) {
        int g = blk*256 + t;
        int idx = g & 16383;
        int lm  = g >> 14;
        int l = lm >> 1, mat = lm & 1;
        int j = idx & 7, q = (idx >> 3) & 3, n = (idx >> 5) & 127, kc = idx >> 12;
        int k = kc*32 + q*8 + j;
        const float* W = (mat == 0 ? W2 : Wc1) + l*HID_*HID_;
        Wp[g] = f2bf(W[k*HID_ + n]);
        return;
    }
    blk -= PACK_BLKS_;
    if (blk < EDGE_BLKS_) {
        int g = blk*256 + t;                  // [0, 83200)
        int b = g / NE_, e = g % NE_;
        if (e < EHH_) return;                 // hh edges handled by sort phase
        int k = e - EHH_;
        int r = k / NH_; int cc = k % NH_; int c = H_ + cc;
        erow[g] = r; ecol[g] = c;
        emk[g] = em_hv[(b*H_ + r)*NH_ + cc];
        ebd[g] = bond [(b*H_ + r)*NH_ + cc];
        return;
    }
    blk -= EDGE_BLKS_;
    if (blk < SORT_BLKS_) {
        // counting-sort the 400 hh edges of batch b by row -> long runs for agg
        int b = blk;
        __shared__ int scnt[64];
        __shared__ int srow[EHH_], scol[EHH_];
        __shared__ float sem[EHH_];
        if (t < 64) scnt[t] = 0;
        __syncthreads();
        for (int e = t; e < EHH_; e += 256) {
            int r = ehh[(b*EHH_ + e)*2 + 0];
            srow[e] = r;
            scol[e] = ehh[(b*EHH_ + e)*2 + 1];
            sem[e]  = em_hh[b*EHH_ + e];
            atomicAdd(&scnt[r], 1);
        }
        __syncthreads();
        if (t == 0) {
            int acc = 0;
            for (int i = 0; i < H_; ++i) { int v = scnt[i]; scnt[i] = acc; acc += v; }
        }
        __syncthreads();
        for (int e = t; e < EHH_; e += 256) {
            int r = srow[e];
            int pos = atomicAdd(&scnt[r], 1);
            int g = b*NE_ + pos;
            erow[g] = r; ecol[g] = scol[e]; emk[g] = sem[e]; ebd[g] = 0.0f;
        }
        return;
    }
    blk -= SORT_BLKS_;
    if (blk < HROW_BLKS_) {
        // h-node layer-0 projections; fold b1 and t*w160 into hiW1
        int g = blk*256 + t;                 // [0, 51200)
        int node = g >> 7, col = g & 127;    // node = b*H + h
        int b = node / H_;
        int label = lab_h[node], pos = pos_h[node];
        int aa = pep[b*15 + pos - 1];
        const float* W1l = W1;               // layer 0
        float hi = W1l[label*HID_ + col]
                 + W1l[(44 + aa)*HID_ + col]
                 + W1l[(64 + pos - 1)*HID_ + col]
                 + b1[col]
                 + t_in[b] * W1l[160*HID_ + col];
        float hj = W1l[(FDIM_ + label)*HID_ + col]
                 + W1l[(FDIM_ + 44 + aa)*HID_ + col]
                 + W1l[(FDIM_ + 64 + pos - 1)*HID_ + col];
        int h = node % H_;
        #pragma unroll
        for (int s = 0; s < S_; ++s) {
            int row = (b*S_ + s)*H_ + h;
            hiW1[(size_t)row*HID_ + col] = hi;
            hjW1[(size_t)row*HID_ + col] = hj;
        }
        return;
    }
    blk -= HROW_BLKS_;
    if (blk < FEAT_BLKS_) {
        int g = blk*256 + t;                 // [0, 32000)
        int node = g / FS_, f = g % FS_;     // node = b*H + h
        int b = node / H_, h = node % H_;
        int label = lab_h[node], pos = pos_h[node];
        int aa = pep[b*15 + pos - 1];
        float v = 0.f;
        if (f < 44)      v = (f == label)          ? 1.0f : 0.0f;
        else if (f < 64) v = ((f - 44) == aa)      ? 1.0f : 0.0f;
        else if (f < 79) v = ((f - 64) == pos - 1) ? 1.0f : 0.0f;
        #pragma unroll
        for (int s = 0; s < S_; ++s)
            feat_h[((b*S_ + s)*H_ + h)*FS_ + f] = v;
        return;
    }
    blk -= FEAT_BLKS_;
    if (blk < ZERO_BLKS_) {
        int idx = blk*256 + t;
        if (idx < 52800) ((float4*)agg0)[idx] = make_float4(0.f, 0.f, 0.f, 0.f);
        return;
    }
    blk -= ZERO_BLKS_;
    {
        int g = blk*256 + t;
        if (g >= BS_*NN_) return;
        int bs = g / NN_, n = g % NN_;
        int b = bs / S_;
        if (n < H_) {
            int ba = bound[b*H_ + n];
            for (int d = 0; d < 3; ++d) {
                float v = x_h[(bs*H_ + n)*3 + d] + x_hv[(b*NH_ + ba)*3 + d];
                x[g*4 + d] = v;
                x0h[(bs*H_ + n)*4 + d] = v;
            }
        } else {
            int nh = n - H_;
            for (int d = 0; d < 3; ++d) x[g*4 + d] = x_hv[(b*NH_ + nh)*3 + d];
        }
    }
}

// ============ per-layer: fused MFMA edge MLP + segment aggregation ============
// (256,4): R10 proved (256,6) forces VGPR 56->40 with scratch spills
// (WRITE_SIZE 4.3->56 MB, dur +8 us). Keep the ILP; don't chase occupancy.
__global__ __launch_bounds__(256, 4) void k_edge_mlp(
    const float* __restrict__ x, const float* __restrict__ hiW1,
    const float* __restrict__ hjW1,
    const int* __restrict__ erow, const int* __restrict__ ecol,
    const float* __restrict__ emk, const float* __restrict__ ebd,
    const float* __restrict__ W1,
    const float* __restrict__ b2, const float* __restrict__ bc1,
    const float* __restrict__ Wc2,
    const unsigned short* __restrict__ Wp, int l,
    float* __restrict__ aggx, float* __restrict__ aggm)
{
    __shared__ unsigned short s_m[TE_][MSTR_];   // 17408 B
    __shared__ float s_diff[TE_][4];
    __shared__ float s_db  [TE_][2];             // dist, bond
    __shared__ float s_emk [TE_];
    __shared__ float s_cw  [TE_];                // per-edge cw (shfl-reduced)
    __shared__ int   s_ii  [TE_];                // bs*H + row
    __shared__ int   s_jj  [TE_];                // hjW1 row index

    const int t = threadIdx.x;
    const int lane = t & 63, w = t >> 6;
    const int l15 = lane & 15, q = lane >> 4;

    // ---- setup: per-edge scalars ----
    if (t < TE_) {
        int ge = blockIdx.x*TE_ + t;
        int bs = ge / NE_;
        int e  = ge - bs*NE_;
        int b  = bs / S_;
        int row = erow[b*NE_ + e], col = ecol[b*NE_ + e];
        s_ii[t] = bs*H_ + row;
        s_jj[t] = (col < H_) ? (bs*H_ + col) : (1600 + l*1600 + b*NH_ + (col - H_));
        float dx0 = x[(bs*NN_ + row)*4 + 0] - x[(bs*NN_ + col)*4 + 0];
        float dx1 = x[(bs*NN_ + row)*4 + 1] - x[(bs*NN_ + col)*4 + 1];
        float dx2 = x[(bs*NN_ + row)*4 + 2] - x[(bs*NN_ + col)*4 + 2];
        s_diff[t][0] = dx0; s_diff[t][1] = dx1; s_diff[t][2] = dx2;
        s_db[t][0] = sqrtf(dx0*dx0 + dx1*dx1 + dx2*dx2);
        s_db[t][1] = ebd[b*NE_ + e];
        s_emk[t]   = emk[b*NE_ + e];
    }
    __syncthreads();

    const int mrow = w*16 + l15;   // this lane's A-row (edge)

    // ---- stage 1 (register-direct): b1,t*w160 pre-folded into hiW1 ----
    short8 afrag[4];
    {
        const float* W1l = W1 + l*EDIM_*HID_;
        int ri = s_ii[mrow], rj = s_jj[mrow];
        float dist = s_db[mrow][0], bond = s_db[mrow][1];
        const float* pi = hiW1 + (size_t)ri*HID_ + q*8;
        const float* pj = hjW1 + (size_t)rj*HID_ + q*8;
        #pragma unroll
        for (int kc = 0; kc < 4; ++kc) {
            int k0 = kc*32 + q*8;
            float4 a0 = *(const float4*)(pi + kc*32);
            float4 a1 = *(const float4*)(pi + kc*32 + 4);
            float4 c0 = *(const float4*)(pj + kc*32);
            float4 c1 = *(const float4*)(pj + kc*32 + 4);
            float4 wa0 = *(const float4*)(W1l + 158*HID_ + k0);
            float4 wa1 = *(const float4*)(W1l + 158*HID_ + k0 + 4);
            float4 wb0 = *(const float4*)(W1l + 159*HID_ + k0);
            float4 wb1 = *(const float4*)(W1l + 159*HID_ + k0 + 4);
            short8 fr;
            fr[0] = (short)f2bf(silu_(a0.x + c0.x + dist*wa0.x + bond*wb0.x));
            fr[1] = (short)f2bf(silu_(a0.y + c0.y + dist*wa0.y + bond*wb0.y));
            fr[2] = (short)f2bf(silu_(a0.z + c0.z + dist*wa0.z + bond*wb0.z));
            fr[3] = (short)f2bf(silu_(a0.w + c0.w + dist*wa0.w + bond*wb0.w));
            fr[4] = (short)f2bf(silu_(a1.x + c1.x + dist*wa1.x + bond*wb1.x));
            fr[5] = (short)f2bf(silu_(a1.y + c1.y + dist*wa1.y + bond*wb1.y));
            fr[6] = (short)f2bf(silu_(a1.z + c1.z + dist*wa1.z + bond*wb1.z));
            fr[7] = (short)f2bf(silu_(a1.w + c1.w + dist*wa1.w + bond*wb1.w));
            afrag[kc] = fr;
        }
    }

    // ---- stage 2: m = silu(m1 @ W2 + b2) * emask  (bias in acc init) ----
    {
        const unsigned short* Wp2 = Wp + (size_t)(l*2 + 0)*16384;
        const float* b2l = b2 + l*HID_;
        float em4[4];
        #pragma unroll
        for (int r = 0; r < 4; ++r) em4[r] = s_emk[w*16 + q*4 + r];
        #pragma unroll
        for (int nt = 0; nt < 8; ++nt) {
            int colj = nt*16 + l15;
            float bias = b2l[colj];
            f32x4 c = {bias, bias, bias, bias};
            #pragma unroll
            for (int kc = 0; kc < 4; ++kc) {
                short8 bfrag = *(const short8*)&Wp2[((kc*128 + nt*16 + l15)*4 + q)*8];
                c = __builtin_amdgcn_mfma_f32_16x16x32_bf16(afrag[kc], bfrag, c, 0, 0, 0);
            }
            #pragma unroll
            for (int r = 0; r < 4; ++r)
                s_m[w*16 + q*4 + r][colj] = f2bf(silu_(c[r]) * em4[r]);
        }
    }
    __builtin_amdgcn_wave_barrier();   // wave-private rows: ds_write before ds_read

    // ---- stage 3: cw = silu(m @ Wc1 + bc1) @ Wc2 ----
    {
        short8 af2[4];
        #pragma unroll
        for (int kc = 0; kc < 4; ++kc)
            af2[kc] = *(const short8*)&s_m[mrow][kc*32 + q*8];
        const unsigned short* Wp3 = Wp + (size_t)(l*2 + 1)*16384;
        const float* bc1l = bc1 + l*HID_;
        const float* wc2l = Wc2 + l*HID_;
        float p[4] = {0.f, 0.f, 0.f, 0.f};
        #pragma unroll
        for (int nt = 0; nt < 8; ++nt) {
            int colj = nt*16 + l15;
            float bias = bc1l[colj];
            f32x4 c = {bias, bias, bias, bias};
            #pragma unroll
            for (int kc = 0; kc < 4; ++kc) {
                short8 bfrag = *(const short8*)&Wp3[((kc*128 + nt*16 + l15)*4 + q)*8];
                c = __builtin_amdgcn_mfma_f32_16x16x32_bf16(af2[kc], bfrag, c, 0, 0, 0);
            }
            float wcv = wc2l[colj];
            #pragma unroll
            for (int r = 0; r < 4; ++r)
                p[r] += silu_(c[r]) * wcv;
        }
        // shfl-xor tree reduce across the 16 lanes of this quad (l15 dim):
        // the 16 cw-partials of edge w*16+q*4+r live in contiguous lanes
        // q*16..q*16+15 of wave w -> masks 8,4,2,1 stay intra-group.
        // Replaces the 4.3 KB s_partT round-trip + wave-0 16-read reduce (R9).
        #pragma unroll
        for (int off = 8; off > 0; off >>= 1) {
            #pragma unroll
            for (int r = 0; r < 4; ++r)
                p[r] += __shfl_xor(p[r], off, 64);
        }
        if (l15 == 0)
            *(float4*)&s_cw[w*16 + q*4] = make_float4(p[0], p[1], p[2], p[3]);
    }
    __syncthreads();

    // ---- aggregation: wave 0 = aggx (s_cw broadcast reads); waves 1,2 = aggm ----
    if (t < TE_) {
        float run = 0.f; int ct = s_ii[0];
        int d = lane & 3;                       // lanes 0..2 meaningful
        for (int i2 = 0; i2 < TE_; ++i2) {
            float cwi = s_cw[i2];               // LDS broadcast
            int tg = s_ii[i2];
            if (tg != ct) {
                if (lane < 3) atomicAdd(&aggx[(size_t)ct*4 + d], run);
                run = 0.f; ct = tg;
            }
            run += s_diff[i2][d] * cwi;
        }
        if (lane < 3) atomicAdd(&aggx[(size_t)ct*4 + d], run);
    } else if (t < TE_ + HID_) {
        int j = t - TE_;
        float run = 0.f; int ct = s_ii[0];
        for (int i2 = 0; i2 < TE_; ++i2) {
            int tg = s_ii[i2];
            if (tg != ct) {
                atomicAdd(&aggm[(size_t)ct*HID_ + j], run);
                run = 0.f; ct = tg;
            }
            run += bf2f(s_m[i2][j]);
        }
        atomicAdd(&aggm[(size_t)ct*HID_ + j], run);
    }
}

// ====== per-layer: node update (8 nodes/block) + next-layer W1 (folded) + out ======
__global__ __launch_bounds__(128) void k_update(
    float* __restrict__ feat_h, float* __restrict__ x,
    const float* __restrict__ aggm, const float* __restrict__ aggx,
    const float* __restrict__ Wn1, const float* __restrict__ bn1,
    const float* __restrict__ Wn2, const float* __restrict__ bn2, int l,
    const float* __restrict__ W1, const float* __restrict__ b1,
    const float* __restrict__ t_in,
    float* __restrict__ hiW1, float* __restrict__ hjW1,
    float* __restrict__ zbase, int do_w1,
    const float* __restrict__ x0h, const float* __restrict__ amask,
    float* __restrict__ out)
{
    if (blockIdx.x >= 200) {
        int z = blockIdx.x - 200;
        for (int idx = z*128 + threadIdx.x; idx < 52800; idx += 207*128)
            ((float4*)zbase)[idx] = make_float4(0.f, 0.f, 0.f, 0.f);
        return;
    }
    __shared__ float s_in[8][NDIM_ + 1];
    __shared__ float s_u[8][HID_ + 1];
    int node0 = blockIdx.x * 8;            // bs*H + h
    int t = threadIdx.x;
    for (int idx = t; idx < 8*(NDIM_ + 1); idx += 128) {
        int g = idx / (NDIM_ + 1), k = idx % (NDIM_ + 1);
        float v = 0.f;
        if (k < FDIM_)      v = feat_h[(node0 + g)*FS_ + k];
        else if (k < NDIM_) v = aggm[(size_t)(node0 + g)*HID_ + (k - FDIM_)];
        s_in[g][k] = v;
    }
    __syncthreads();
    const float* Wn1l = Wn1 + l*NDIM_*HID_;
    float acc[8];
    float bv = bn1[l*HID_ + t];
    #pragma unroll
    for (int g = 0; g < 8; ++g) acc[g] = bv;
    for (int k = 0; k < NDIM_; ++k) {
        float wv = Wn1l[k*HID_ + t];
        #pragma unroll
        for (int g = 0; g < 8; ++g) acc[g] += s_in[g][k] * wv;
    }
    #pragma unroll
    for (int g = 0; g < 8; ++g) s_u[g][t] = silu_(acc[g]);
    __syncthreads();
    if (t < FDIM_) {
        const float* Wn2l = Wn2 + l*HID_*FDIM_;
        float acc2[8];
        float b2v = bn2[l*FDIM_ + t];
        #pragma unroll
        for (int g = 0; g < 8; ++g) acc2[g] = b2v;
        for (int k = 0; k < HID_; ++k) {
            float wv = Wn2l[k*FDIM_ + t];
            #pragma unroll
            for (int g = 0; g < 8; ++g) acc2[g] += s_u[g][k] * wv;
        }
        #pragma unroll
        for (int g = 0; g < 8; ++g) {
            float nf = s_in[g][t] + acc2[g];
            feat_h[(node0 + g)*FS_ + t] = nf;
            s_in[g][t] = nf;
        }
    } else if (t >= 96 && t < 120) {
        int idx = t - 96, g = idx / 3, d = idx % 3;
        int node = node0 + g;
        int bs = node / H_, h = node % H_;
        float xv = x[(bs*NN_ + h)*4 + d] + aggx[node*4 + d];
        x[(bs*NN_ + h)*4 + d] = xv;
        if (!do_w1) {
            int b = bs / S_;
            out[node*3 + d] = (xv - x0h[node*4 + d]) * amask[b*H_ + h];
        }
    }
    if (!do_w1) return;
    __syncthreads();
    // ---- next-layer W1 projections (fold b1 + t*w160 into hiW1) ----
    {
        const float* W1n = W1 + (l + 1)*EDIM_*HID_;
        float w160 = W1n[160*HID_ + t];
        float b1v  = b1[(l + 1)*HID_ + t];
        float hia[8], hja[8];
        #pragma unroll
        for (int g = 0; g < 8; ++g) { hia[g] = 0.f; hja[g] = 0.f; }
        for (int f = 0; f < FDIM_; ++f) {
            float wi = W1n[f*HID_ + t];
            float wj = W1n[(FDIM_ + f)*HID_ + t];
            #pragma unroll
            for (int g = 0; g < 8; ++g) {
                float v = s_in[g][f];
                hia[g] += v * wi;
                hja[g] += v * wj;
            }
        }
        #pragma unroll
        for (int g = 0; g < 8; ++g) {
            int node = node0 + g;
            int b = (node / H_) / S_;
            hiW1[(size_t)node*HID_ + t] = hia[g] + b1v + t_in[b]*w160;
            hjW1[(size_t)node*HID_ + t] = hja[g];
        }
    }
}

// ---------------- launch ----------------
extern "C" void kernel_launch(void* const* d_in, const int* in_sizes, int n_in,
                              void* d_out, int out_size, void* d_ws, size_t ws_size,
                              hipStream_t stream)
{
    const float* t_in  = (const float*)d_in[0];
    const float* x_h   = (const float*)d_in[1];
    const float* x_hv  = (const float*)d_in[2];
    const float* bond  = (const float*)d_in[3];
    const float* em_hv = (const float*)d_in[4];
    const float* em_hh = (const float*)d_in[5];
    const float* amask = (const float*)d_in[6];
    const float* W1    = (const float*)d_in[7];
    const float* b1    = (const float*)d_in[8];
    const float* W2    = (const float*)d_in[9];
    const float* b2    = (const float*)d_in[10];
    const float* Wc1   = (const float*)d_in[11];
    const float* bc1   = (const float*)d_in[12];
    const float* Wc2   = (const float*)d_in[13];
    const float* Wn1   = (const float*)d_in[14];
    const float* bn1   = (const float*)d_in[15];
    const float* Wn2   = (const float*)d_in[16];
    const float* bn2   = (const float*)d_in[17];
    const int* pep     = (const int*)d_in[18];
    const int* lab_hv  = (const int*)d_in[19];
    const int* lab_h   = (const int*)d_in[20];
    const int* pos_hv  = (const int*)d_in[21];
    const int* pos_h   = (const int*)d_in[22];
    const int* ehh     = (const int*)d_in[23];
    const int* bound   = (const int*)d_in[24];

    float* ws     = (float*)d_ws;
    float* feat_h = ws + OFF_FEATH;
    float* x      = ws + OFF_X;
    float* x0h    = ws + OFF_X0H;
    int*   erow   = (int*)(ws + OFF_EROW);
    int*   ecol   = (int*)(ws + OFF_ECOL);
    float* emk    = ws + OFF_EMASK;
    float* ebd    = ws + OFF_EBOND;
    float* hiW1   = ws + OFF_HIW1;
    float* hjW1   = ws + OFF_HJW1;
    unsigned short* Wp = (unsigned short*)(ws + OFF_WP);

    hipLaunchKernelGGL(k_setup, dim3(SETUP_BLKS_), dim3(256), 0, stream,
                       x_h, x_hv, bound, ehh, em_hh, em_hv, bond,
                       W1, b1, t_in, W2, Wc1,
                       lab_h, pos_h, lab_hv, pos_hv, pep,
                       feat_h, x, x0h, erow, ecol, emk, ebd,
                       hiW1, hjW1, ws + OFF_AGG0, Wp);

    for (int l = 0; l < L_; ++l) {
        float* aggx_l = ws + OFF_AGG0 + (size_t)l*AGGSTRIDE_;
        float* aggm_l = aggx_l + 6400;
        hipLaunchKernelGGL(k_edge_mlp, dim3(TOTE_/TE_), dim3(256), 0, stream,
                           x, hiW1, hjW1, erow, ecol, emk, ebd,
                           W1, b2, bc1, Wc2, Wp, l, aggx_l, aggm_l);
        int do_w1 = (l == 0);
        float* zbase = ws + OFF_AGG0 + (size_t)(l + 1)*AGGSTRIDE_;
        hipLaunchKernelGGL(k_update, dim3(do_w1 ? 407 : 200), dim3(128), 0, stream,
                           feat_h, x, aggm_l, aggx_l, Wn1, bn1, Wn2, bn2, l,
                           W1, b1, t_in, hiW1, hjW1,
                           do_w1 ? zbase : (ws + OFF_AGG0), do_w1,
                           x0h, amask, (float*)d_out);
    }
}

// Round 12
// 431.713 us; speedup vs baseline: 1.0361x; 1.0194x over previous
//
#include <hip/hip_runtime.h>
#include <math.h>

// Problem constants
#define B_     8
#define S_     4
#define H_     50
#define NH_    200
#define EHH_   400
#define L_     2
#define HID_   128
#define FDIM_  79          // 44 + 20 + 15
#define EDIM_  161         // 2*FDIM + 3
#define NN_    250         // H + NH
#define NE_    10400       // EHH + H*NH
#define BS_    32          // B*S
#define TOTE_  (BS_*NE_)   // 332800
#define FS_    80          // feat row stride
#define TE_    64          // edges per block in edge kernel
#define MSTR_  136         // s_m stride in bf16 (128 + 8)
#define NDIM_  207         // FDIM + HID

// Workspace layout (float offsets)
#define OFF_FEATH  0         // BS*H*80 = 128000
#define OFF_X      128000    // BS*NN*4 = 32000
#define OFF_X0H    160000    // BS*H*4  = 6400
#define OFF_EROW   166400    // 83200 (int)
#define OFF_ECOL   249600    // 83200 (int)
#define OFF_EMASK  332800    // 83200
#define OFF_EBOND  416000    // 83200
#define OFF_AGG0   499200    // aggx0(6400) + aggm0(204800); agg1 contiguous after
#define OFF_AGG1   710400    // 211200
#define OFF_HIW1   921600    // fp32 1600*128 (b1 + t*w160 folded in)
#define OFF_HJW1   1126400   // fp32 4800*128: [0,1600) h cur | [1600,3200) hv l0 | [3200,4800) hv l1
#define OFF_WP     1740800   // 65536 ushort
#define AGGSTRIDE_ 211200

typedef __attribute__((ext_vector_type(8))) short short8;
typedef __attribute__((ext_vector_type(4))) float f32x4;

__device__ __forceinline__ float silu_(float v) {
    return v * __builtin_amdgcn_rcpf(1.0f + __expf(-v));
}
__device__ __forceinline__ unsigned short f2bf(float f) {
    unsigned int u = __float_as_uint(f);
    unsigned int r = (u + 0x7fffu + ((u >> 16) & 1u)) >> 16;
    return (unsigned short)r;
}
__device__ __forceinline__ float bf2f(unsigned short v) {
    return __uint_as_float(((unsigned int)v) << 16);
}

// ================= fused setup =================
#define HV_BLKS_    1600   // heavy hjW1 both layers: 409600
#define PACK_BLKS_  256    // 65536
#define EDGE_BLKS_  325    // grid edges of 83200 (skip e<400)
#define SORT_BLKS_  8      // counting-sort hh edges by row, per b
#define HROW_BLKS_  200    // 400*128
#define FEAT_BLKS_  125    // 400*80
#define ZERO_BLKS_  413    // 105600 float4 = BOTH agg buffers (moved from k_update)
#define XI_BLKS_    32     // 8000
#define SETUP_BLKS_ (HV_BLKS_ + PACK_BLKS_ + EDGE_BLKS_ + SORT_BLKS_ + HROW_BLKS_ + FEAT_BLKS_ + ZERO_BLKS_ + XI_BLKS_)

__global__ __launch_bounds__(256) void k_setup(
    const float* __restrict__ x_h, const float* __restrict__ x_hv,
    const int* __restrict__ bound,
    const int* __restrict__ ehh, const float* __restrict__ em_hh,
    const float* __restrict__ em_hv, const float* __restrict__ bond,
    const float* __restrict__ W1, const float* __restrict__ b1,
    const float* __restrict__ t_in,
    const float* __restrict__ W2, const float* __restrict__ Wc1,
    const int* __restrict__ lab_h, const int* __restrict__ pos_h,
    const int* __restrict__ lab_hv, const int* __restrict__ pos_hv,
    const int* __restrict__ pep,
    float* __restrict__ feat_h,
    float* __restrict__ x, float* __restrict__ x0h,
    int* __restrict__ erow, int* __restrict__ ecol,
    float* __restrict__ emk, float* __restrict__ ebd,
    float* __restrict__ hiW1, float* __restrict__ hjW1,
    float* __restrict__ agg0,
    unsigned short* __restrict__ Wp)
{
    int blk = blockIdx.x, t = threadIdx.x;
    if (blk < HV_BLKS_) {
        int g = blk*256 + t;                 // [0, 409600)
        int l = g / 204800;
        int r = g - l*204800;
        int node = r >> 7, col = r & 127;    // node = b*NH + nh
        int b = node / NH_;
        int label = lab_hv[node], pos = pos_hv[node];
        int aa = pep[b*15 + pos - 1];
        const float* W1l = W1 + l*EDIM_*HID_;
        float hj = W1l[(FDIM_ + label)*HID_ + col]
                 + W1l[(FDIM_ + 44 + aa)*HID_ + col]
                 + W1l[(FDIM_ + 64 + pos - 1)*HID_ + col];
        hjW1[(size_t)(1600 + l*1600 + node)*HID_ + col] = hj;
        return;
    }
    blk -= HV_BLKS_;
    if (blk < PACK_BLKS_) {
        int g = blk*256 + t;
        int idx = g & 16383;
        int lm  = g >> 14;
        int l = lm >> 1, mat = lm & 1;
        int j = idx & 7, q = (idx >> 3) & 3, n = (idx >> 5) & 127, kc = idx >> 12;
        int k = kc*32 + q*8 + j;
        const float* W = (mat == 0 ? W2 : Wc1) + l*HID_*HID_;
        Wp[g] = f2bf(W[k*HID_ + n]);
        return;
    }
    blk -= PACK_BLKS_;
    if (blk < EDGE_BLKS_) {
        int g = blk*256 + t;                  // [0, 83200)
        int b = g / NE_, e = g % NE_;
        if (e < EHH_) return;                 // hh edges handled by sort phase
        int k = e - EHH_;
        int r = k / NH_; int cc = k % NH_; int c = H_ + cc;
        erow[g] = r; ecol[g] = c;
        emk[g] = em_hv[(b*H_ + r)*NH_ + cc];
        ebd[g] = bond [(b*H_ + r)*NH_ + cc];
        return;
    }
    blk -= EDGE_BLKS_;
    if (blk < SORT_BLKS_) {
        // counting-sort the 400 hh edges of batch b by row -> long runs for agg
        int b = blk;
        __shared__ int scnt[64];
        __shared__ int srow[EHH_], scol[EHH_];
        __shared__ float sem[EHH_];
        if (t < 64) scnt[t] = 0;
        __syncthreads();
        for (int e = t; e < EHH_; e += 256) {
            int r = ehh[(b*EHH_ + e)*2 + 0];
            srow[e] = r;
            scol[e] = ehh[(b*EHH_ + e)*2 + 1];
            sem[e]  = em_hh[b*EHH_ + e];
            atomicAdd(&scnt[r], 1);
        }
        __syncthreads();
        if (t == 0) {
            int acc = 0;
            for (int i = 0; i < H_; ++i) { int v = scnt[i]; scnt[i] = acc; acc += v; }
        }
        __syncthreads();
        for (int e = t; e < EHH_; e += 256) {
            int r = srow[e];
            int pos = atomicAdd(&scnt[r], 1);
            int g = b*NE_ + pos;
            erow[g] = r; ecol[g] = scol[e]; emk[g] = sem[e]; ebd[g] = 0.0f;
        }
        return;
    }
    blk -= SORT_BLKS_;
    if (blk < HROW_BLKS_) {
        // h-node layer-0 projections; fold b1 and t*w160 into hiW1
        int g = blk*256 + t;                 // [0, 51200)
        int node = g >> 7, col = g & 127;    // node = b*H + h
        int b = node / H_;
        int label = lab_h[node], pos = pos_h[node];
        int aa = pep[b*15 + pos - 1];
        const float* W1l = W1;               // layer 0
        float hi = W1l[label*HID_ + col]
                 + W1l[(44 + aa)*HID_ + col]
                 + W1l[(64 + pos - 1)*HID_ + col]
                 + b1[col]
                 + t_in[b] * W1l[160*HID_ + col];
        float hj = W1l[(FDIM_ + label)*HID_ + col]
                 + W1l[(FDIM_ + 44 + aa)*HID_ + col]
                 + W1l[(FDIM_ + 64 + pos - 1)*HID_ + col];
        int h = node % H_;
        #pragma unroll
        for (int s = 0; s < S_; ++s) {
            int row = (b*S_ + s)*H_ + h;
            hiW1[(size_t)row*HID_ + col] = hi;
            hjW1[(size_t)row*HID_ + col] = hj;
        }
        return;
    }
    blk -= HROW_BLKS_;
    if (blk < FEAT_BLKS_) {
        int g = blk*256 + t;                 // [0, 32000)
        int node = g / FS_, f = g % FS_;     // node = b*H + h
        int b = node / H_, h = node % H_;
        int label = lab_h[node], pos = pos_h[node];
        int aa = pep[b*15 + pos - 1];
        float v = 0.f;
        if (f < 44)      v = (f == label)          ? 1.0f : 0.0f;
        else if (f < 64) v = ((f - 44) == aa)      ? 1.0f : 0.0f;
        else if (f < 79) v = ((f - 64) == pos - 1) ? 1.0f : 0.0f;
        #pragma unroll
        for (int s = 0; s < S_; ++s)
            feat_h[((b*S_ + s)*H_ + h)*FS_ + f] = v;
        return;
    }
    blk -= FEAT_BLKS_;
    if (blk < ZERO_BLKS_) {
        // zero BOTH layers' agg buffers up front (moved out of k_update(l=0)
        // so the 200 update blocks own the inter-edge critical path alone)
        int idx = blk*256 + t;
        if (idx < 105600) ((float4*)agg0)[idx] = make_float4(0.f, 0.f, 0.f, 0.f);
        return;
    }
    blk -= ZERO_BLKS_;
    {
        int g = blk*256 + t;
        if (g >= BS_*NN_) return;
        int bs = g / NN_, n = g % NN_;
        int b = bs / S_;
        if (n < H_) {
            int ba = bound[b*H_ + n];
            for (int d = 0; d < 3; ++d) {
                float v = x_h[(bs*H_ + n)*3 + d] + x_hv[(b*NH_ + ba)*3 + d];
                x[g*4 + d] = v;
                x0h[(bs*H_ + n)*4 + d] = v;
            }
        } else {
            int nh = n - H_;
            for (int d = 0; d < 3; ++d) x[g*4 + d] = x_hv[(b*NH_ + nh)*3 + d];
        }
    }
}

// ============ per-layer: fused MFMA edge MLP + segment aggregation ============
// (256,4): R10 proved (256,6) forces VGPR 56->40 with scratch spills.
// partT layout: R11 proved the shfl-xor tree costs +8 VGPR and +4 us.
// This is R9's exact edge kernel — the measured optimum (132.2 us).
__global__ __launch_bounds__(256, 4) void k_edge_mlp(
    const float* __restrict__ x, const float* __restrict__ hiW1,
    const float* __restrict__ hjW1,
    const int* __restrict__ erow, const int* __restrict__ ecol,
    const float* __restrict__ emk, const float* __restrict__ ebd,
    const float* __restrict__ W1,
    const float* __restrict__ b2, const float* __restrict__ bc1,
    const float* __restrict__ Wc2,
    const unsigned short* __restrict__ Wp, int l,
    float* __restrict__ aggx, float* __restrict__ aggm)
{
    __shared__ unsigned short s_m[TE_][MSTR_];   // 17408 B
    __shared__ float s_partT[16][68];            // 4352 B
    __shared__ float s_diff[TE_][4];
    __shared__ float s_db  [TE_][2];             // dist, bond
    __shared__ float s_emk [TE_];
    __shared__ int   s_ii  [TE_];                // bs*H + row
    __shared__ int   s_jj  [TE_];                // hjW1 row index

    const int t = threadIdx.x;
    const int lane = t & 63, w = t >> 6;
    const int l15 = lane & 15, q = lane >> 4;

    // ---- setup: per-edge scalars ----
    if (t < TE_) {
        int ge = blockIdx.x*TE_ + t;
        int bs = ge / NE_;
        int e  = ge - bs*NE_;
        int b  = bs / S_;
        int row = erow[b*NE_ + e], col = ecol[b*NE_ + e];
        s_ii[t] = bs*H_ + row;
        s_jj[t] = (col < H_) ? (bs*H_ + col) : (1600 + l*1600 + b*NH_ + (col - H_));
        float dx0 = x[(bs*NN_ + row)*4 + 0] - x[(bs*NN_ + col)*4 + 0];
        float dx1 = x[(bs*NN_ + row)*4 + 1] - x[(bs*NN_ + col)*4 + 1];
        float dx2 = x[(bs*NN_ + row)*4 + 2] - x[(bs*NN_ + col)*4 + 2];
        s_diff[t][0] = dx0; s_diff[t][1] = dx1; s_diff[t][2] = dx2;
        s_db[t][0] = sqrtf(dx0*dx0 + dx1*dx1 + dx2*dx2);
        s_db[t][1] = ebd[b*NE_ + e];
        s_emk[t]   = emk[b*NE_ + e];
    }
    __syncthreads();

    const int mrow = w*16 + l15;   // this lane's A-row (edge)

    // ---- stage 1 (register-direct): b1,t*w160 pre-folded into hiW1 ----
    short8 afrag[4];
    {
        const float* W1l = W1 + l*EDIM_*HID_;
        int ri = s_ii[mrow], rj = s_jj[mrow];
        float dist = s_db[mrow][0], bond = s_db[mrow][1];
        const float* pi = hiW1 + (size_t)ri*HID_ + q*8;
        const float* pj = hjW1 + (size_t)rj*HID_ + q*8;
        #pragma unroll
        for (int kc = 0; kc < 4; ++kc) {
            int k0 = kc*32 + q*8;
            float4 a0 = *(const float4*)(pi + kc*32);
            float4 a1 = *(const float4*)(pi + kc*32 + 4);
            float4 c0 = *(const float4*)(pj + kc*32);
            float4 c1 = *(const float4*)(pj + kc*32 + 4);
            float4 wa0 = *(const float4*)(W1l + 158*HID_ + k0);
            float4 wa1 = *(const float4*)(W1l + 158*HID_ + k0 + 4);
            float4 wb0 = *(const float4*)(W1l + 159*HID_ + k0);
            float4 wb1 = *(const float4*)(W1l + 159*HID_ + k0 + 4);
            short8 fr;
            fr[0] = (short)f2bf(silu_(a0.x + c0.x + dist*wa0.x + bond*wb0.x));
            fr[1] = (short)f2bf(silu_(a0.y + c0.y + dist*wa0.y + bond*wb0.y));
            fr[2] = (short)f2bf(silu_(a0.z + c0.z + dist*wa0.z + bond*wb0.z));
            fr[3] = (short)f2bf(silu_(a0.w + c0.w + dist*wa0.w + bond*wb0.w));
            fr[4] = (short)f2bf(silu_(a1.x + c1.x + dist*wa1.x + bond*wb1.x));
            fr[5] = (short)f2bf(silu_(a1.y + c1.y + dist*wa1.y + bond*wb1.y));
            fr[6] = (short)f2bf(silu_(a1.z + c1.z + dist*wa1.z + bond*wb1.z));
            fr[7] = (short)f2bf(silu_(a1.w + c1.w + dist*wa1.w + bond*wb1.w));
            afrag[kc] = fr;
        }
    }

    // ---- stage 2: m = silu(m1 @ W2 + b2) * emask  (bias in acc init) ----
    {
        const unsigned short* Wp2 = Wp + (size_t)(l*2 + 0)*16384;
        const float* b2l = b2 + l*HID_;
        float em4[4];
        #pragma unroll
        for (int r = 0; r < 4; ++r) em4[r] = s_emk[w*16 + q*4 + r];
        #pragma unroll
        for (int nt = 0; nt < 8; ++nt) {
            int colj = nt*16 + l15;
            float bias = b2l[colj];
            f32x4 c = {bias, bias, bias, bias};
            #pragma unroll
            for (int kc = 0; kc < 4; ++kc) {
                short8 bfrag = *(const short8*)&Wp2[((kc*128 + nt*16 + l15)*4 + q)*8];
                c = __builtin_amdgcn_mfma_f32_16x16x32_bf16(afrag[kc], bfrag, c, 0, 0, 0);
            }
            #pragma unroll
            for (int r = 0; r < 4; ++r)
                s_m[w*16 + q*4 + r][colj] = f2bf(silu_(c[r]) * em4[r]);
        }
    }
    __builtin_amdgcn_wave_barrier();   // wave-private rows: ds_write before ds_read

    // ---- stage 3: cw = silu(m @ Wc1 + bc1) @ Wc2 ----
    {
        short8 af2[4];
        #pragma unroll
        for (int kc = 0; kc < 4; ++kc)
            af2[kc] = *(const short8*)&s_m[mrow][kc*32 + q*8];
        const unsigned short* Wp3 = Wp + (size_t)(l*2 + 1)*16384;
        const float* bc1l = bc1 + l*HID_;
        const float* wc2l = Wc2 + l*HID_;
        float p[4] = {0.f, 0.f, 0.f, 0.f};
        #pragma unroll
        for (int nt = 0; nt < 8; ++nt) {
            int colj = nt*16 + l15;
            float bias = bc1l[colj];
            f32x4 c = {bias, bias, bias, bias};
            #pragma unroll
            for (int kc = 0; kc < 4; ++kc) {
                short8 bfrag = *(const short8*)&Wp3[((kc*128 + nt*16 + l15)*4 + q)*8];
                c = __builtin_amdgcn_mfma_f32_16x16x32_bf16(af2[kc], bfrag, c, 0, 0, 0);
            }
            float wcv = wc2l[colj];
            #pragma unroll
            for (int r = 0; r < 4; ++r)
                p[r] += silu_(c[r]) * wcv;
        }
        *(float4*)&s_partT[l15][w*16 + q*4] = make_float4(p[0], p[1], p[2], p[3]);
    }
    __syncthreads();

    // ---- aggregation: wave 0 = cw reduce + aggx via shuffle; waves 1,2 = aggm ----
    if (t < TE_) {
        float cwv = 0.f;
        #pragma unroll
        for (int c = 0; c < 16; ++c) cwv += s_partT[c][t];
        float run = 0.f; int ct = s_ii[0];
        int d = lane & 3;                       // lanes 0..2 meaningful
        for (int i2 = 0; i2 < TE_; ++i2) {
            float cwi = __shfl(cwv, i2, 64);
            int tg = s_ii[i2];
            if (tg != ct) {
                if (lane < 3) atomicAdd(&aggx[(size_t)ct*4 + d], run);
                run = 0.f; ct = tg;
            }
            run += s_diff[i2][d] * cwi;
        }
        if (lane < 3) atomicAdd(&aggx[(size_t)ct*4 + d], run);
    } else if (t < TE_ + HID_) {
        int j = t - TE_;
        float run = 0.f; int ct = s_ii[0];
        for (int i2 = 0; i2 < TE_; ++i2) {
            int tg = s_ii[i2];
            if (tg != ct) {
                atomicAdd(&aggm[(size_t)ct*HID_ + j], run);
                run = 0.f; ct = tg;
            }
            run += bf2f(s_m[i2][j]);
        }
        atomicAdd(&aggm[(size_t)ct*HID_ + j], run);
    }
}

// ====== per-layer: node update (8 nodes/block) + next-layer W1 (folded) + out ======
__global__ __launch_bounds__(128) void k_update(
    float* __restrict__ feat_h, float* __restrict__ x,
    const float* __restrict__ aggm, const float* __restrict__ aggx,
    const float* __restrict__ Wn1, const float* __restrict__ bn1,
    const float* __restrict__ Wn2, const float* __restrict__ bn2, int l,
    const float* __restrict__ W1, const float* __restrict__ b1,
    const float* __restrict__ t_in,
    float* __restrict__ hiW1, float* __restrict__ hjW1, int do_w1,
    const float* __restrict__ x0h, const float* __restrict__ amask,
    float* __restrict__ out)
{
    __shared__ float s_in[8][NDIM_ + 1];
    __shared__ float s_u[8][HID_ + 1];
    int node0 = blockIdx.x * 8;            // bs*H + h
    int t = threadIdx.x;
    for (int idx = t; idx < 8*(NDIM_ + 1); idx += 128) {
        int g = idx / (NDIM_ + 1), k = idx % (NDIM_ + 1);
        float v = 0.f;
        if (k < FDIM_)      v = feat_h[(node0 + g)*FS_ + k];
        else if (k < NDIM_) v = aggm[(size_t)(node0 + g)*HID_ + (k - FDIM_)];
        s_in[g][k] = v;
    }
    __syncthreads();
    const float* Wn1l = Wn1 + l*NDIM_*HID_;
    float acc[8];
    float bv = bn1[l*HID_ + t];
    #pragma unroll
    for (int g = 0; g < 8; ++g) acc[g] = bv;
    for (int k = 0; k < NDIM_; ++k) {
        float wv = Wn1l[k*HID_ + t];
        #pragma unroll
        for (int g = 0; g < 8; ++g) acc[g] += s_in[g][k] * wv;
    }
    #pragma unroll
    for (int g = 0; g < 8; ++g) s_u[g][t] = silu_(acc[g]);
    __syncthreads();
    if (t < FDIM_) {
        const float* Wn2l = Wn2 + l*HID_*FDIM_;
        float acc2[8];
        float b2v = bn2[l*FDIM_ + t];
        #pragma unroll
        for (int g = 0; g < 8; ++g) acc2[g] = b2v;
        for (int k = 0; k < HID_; ++k) {
            float wv = Wn2l[k*FDIM_ + t];
            #pragma unroll
            for (int g = 0; g < 8; ++g) acc2[g] += s_u[g][k] * wv;
        }
        #pragma unroll
        for (int g = 0; g < 8; ++g) {
            float nf = s_in[g][t] + acc2[g];
            feat_h[(node0 + g)*FS_ + t] = nf;
            s_in[g][t] = nf;
        }
    } else if (t >= 96 && t < 120) {
        int idx = t - 96, g = idx / 3, d = idx % 3;
        int node = node0 + g;
        int bs = node / H_, h = node % H_;
        float xv = x[(bs*NN_ + h)*4 + d] + aggx[node*4 + d];
        x[(bs*NN_ + h)*4 + d] = xv;
        if (!do_w1) {
            int b = bs / S_;
            out[node*3 + d] = (xv - x0h[node*4 + d]) * amask[b*H_ + h];
        }
    }
    if (!do_w1) return;
    __syncthreads();
    // ---- next-layer W1 projections (fold b1 + t*w160 into hiW1) ----
    {
        const float* W1n = W1 + (l + 1)*EDIM_*HID_;
        float w160 = W1n[160*HID_ + t];
        float b1v  = b1[(l + 1)*HID_ + t];
        float hia[8], hja[8];
        #pragma unroll
        for (int g = 0; g < 8; ++g) { hia[g] = 0.f; hja[g] = 0.f; }
        for (int f = 0; f < FDIM_; ++f) {
            float wi = W1n[f*HID_ + t];
            float wj = W1n[(FDIM_ + f)*HID_ + t];
            #pragma unroll
            for (int g = 0; g < 8; ++g) {
                float v = s_in[g][f];
                hia[g] += v * wi;
                hja[g] += v * wj;
            }
        }
        #pragma unroll
        for (int g = 0; g < 8; ++g) {
            int node = node0 + g;
            int b = (node / H_) / S_;
            hiW1[(size_t)node*HID_ + t] = hia[g] + b1v + t_in[b]*w160;
            hjW1[(size_t)node*HID_ + t] = hja[g];
        }
    }
}

// ---------------- launch ----------------
extern "C" void kernel_launch(void* const* d_in, const int* in_sizes, int n_in,
                              void* d_out, int out_size, void* d_ws, size_t ws_size,
                              hipStream_t stream)
{
    const float* t_in  = (const float*)d_in[0];
    const float* x_h   = (const float*)d_in[1];
    const float* x_hv  = (const float*)d_in[2];
    const float* bond  = (const float*)d_in[3];
    const float* em_hv = (const float*)d_in[4];
    const float* em_hh = (const float*)d_in[5];
    const float* amask = (const float*)d_in[6];
    const float* W1    = (const float*)d_in[7];
    const float* b1    = (const float*)d_in[8];
    const float* W2    = (const float*)d_in[9];
    const float* b2    = (const float*)d_in[10];
    const float* Wc1   = (const float*)d_in[11];
    const float* bc1   = (const float*)d_in[12];
    const float* Wc2   = (const float*)d_in[13];
    const float* Wn1   = (const float*)d_in[14];
    const float* bn1   = (const float*)d_in[15];
    const float* Wn2   = (const float*)d_in[16];
    const float* bn2   = (const float*)d_in[17];
    const int* pep     = (const int*)d_in[18];
    const int* lab_hv  = (const int*)d_in[19];
    const int* lab_h   = (const int*)d_in[20];
    const int* pos_hv  = (const int*)d_in[21];
    const int* pos_h   = (const int*)d_in[22];
    const int* ehh     = (const int*)d_in[23];
    const int* bound   = (const int*)d_in[24];

    float* ws     = (float*)d_ws;
    float* feat_h = ws + OFF_FEATH;
    float* x      = ws + OFF_X;
    float* x0h    = ws + OFF_X0H;
    int*   erow   = (int*)(ws + OFF_EROW);
    int*   ecol   = (int*)(ws + OFF_ECOL);
    float* emk    = ws + OFF_EMASK;
    float* ebd    = ws + OFF_EBOND;
    float* hiW1   = ws + OFF_HIW1;
    float* hjW1   = ws + OFF_HJW1;
    unsigned short* Wp = (unsigned short*)(ws + OFF_WP);

    hipLaunchKernelGGL(k_setup, dim3(SETUP_BLKS_), dim3(256), 0, stream,
                       x_h, x_hv, bound, ehh, em_hh, em_hv, bond,
                       W1, b1, t_in, W2, Wc1,
                       lab_h, pos_h, lab_hv, pos_hv, pep,
                       feat_h, x, x0h, erow, ecol, emk, ebd,
                       hiW1, hjW1, ws + OFF_AGG0, Wp);

    for (int l = 0; l < L_; ++l) {
        float* aggx_l = ws + OFF_AGG0 + (size_t)l*AGGSTRIDE_;
        float* aggm_l = aggx_l + 6400;
        hipLaunchKernelGGL(k_edge_mlp, dim3(TOTE_/TE_), dim3(256), 0, stream,
                           x, hiW1, hjW1, erow, ecol, emk, ebd,
                           W1, b2, bc1, Wc2, Wp, l, aggx_l, aggm_l);
        int do_w1 = (l == 0);
        hipLaunchKernelGGL(k_update, dim3(200), dim3(128), 0, stream,
                           feat_h, x, aggm_l, aggx_l, Wn1, bn1, Wn2, bn2, l,
                           W1, b1, t_in, hiW1, hjW1, do_w1,
                           x0h, amask, (float*)d_out);
    }
}

// Round 13
// 431.349 us; speedup vs baseline: 1.0370x; 1.0008x over previous
//
#include <hip/hip_runtime.h>
#include <math.h>

// Problem constants
#define B_     8
#define S_     4
#define H_     50
#define NH_    200
#define EHH_   400
#define L_     2
#define HID_   128
#define FDIM_  79          // 44 + 20 + 15
#define EDIM_  161         // 2*FDIM + 3
#define NN_    250         // H + NH
#define NE_    10400       // EHH + H*NH
#define BS_    32          // B*S
#define TOTE_  (BS_*NE_)   // 332800
#define FS_    80          // feat row stride
#define TE_    64          // edges per block in edge kernel
#define MSTR_  136         // s_m stride in bf16 (128 + 8)
#define NDIM_  207         // FDIM + HID

// Workspace layout (float offsets)
#define OFF_FEATH  0         // BS*H*80 = 128000
#define OFF_X      128000    // BS*NN*4 = 32000
#define OFF_X0H    160000    // BS*H*4  = 6400
#define OFF_EROW   166400    // 83200 (int)
#define OFF_ECOL   249600    // 83200 (int)
#define OFF_EMASK  332800    // 83200
#define OFF_EBOND  416000    // 83200
#define OFF_AGG0   499200    // aggx0(6400) + aggm0(204800) = 211200
#define OFF_AGG1   710400    // 211200
#define OFF_HIW1   921600    // fp32 1600*128 (b1 + t*w160 folded in)
#define OFF_HJW1   1126400   // fp32 4800*128: [0,1600) h cur | [1600,3200) hv l0 | [3200,4800) hv l1
#define OFF_WP     1740800   // 65536 ushort
#define AGGSTRIDE_ 211200

typedef __attribute__((ext_vector_type(8))) short short8;
typedef __attribute__((ext_vector_type(4))) float f32x4;

__device__ __forceinline__ float silu_(float v) {
    return v * __builtin_amdgcn_rcpf(1.0f + __expf(-v));
}
__device__ __forceinline__ unsigned short f2bf(float f) {
    unsigned int u = __float_as_uint(f);
    unsigned int r = (u + 0x7fffu + ((u >> 16) & 1u)) >> 16;
    return (unsigned short)r;
}
__device__ __forceinline__ float bf2f(unsigned short v) {
    return __uint_as_float(((unsigned int)v) << 16);
}

// ================= fused setup =================
#define HV_BLKS_    1600   // heavy hjW1 both layers: 409600
#define PACK_BLKS_  256    // 65536
#define EDGE_BLKS_  325    // grid edges of 83200 (skip e<400)
#define SORT_BLKS_  8      // counting-sort hh edges by row, per b
#define HROW_BLKS_  200    // 400*128
#define FEAT_BLKS_  125    // 400*80
#define ZERO_BLKS_  207    // 52800 float4 (agg0 only; agg1 zeroed in k_update(l=0))
#define XI_BLKS_    32     // 8000
#define SETUP_BLKS_ (HV_BLKS_ + PACK_BLKS_ + EDGE_BLKS_ + SORT_BLKS_ + HROW_BLKS_ + FEAT_BLKS_ + ZERO_BLKS_ + XI_BLKS_)

__global__ __launch_bounds__(256) void k_setup(
    const float* __restrict__ x_h, const float* __restrict__ x_hv,
    const int* __restrict__ bound,
    const int* __restrict__ ehh, const float* __restrict__ em_hh,
    const float* __restrict__ em_hv, const float* __restrict__ bond,
    const float* __restrict__ W1, const float* __restrict__ b1,
    const float* __restrict__ t_in,
    const float* __restrict__ W2, const float* __restrict__ Wc1,
    const int* __restrict__ lab_h, const int* __restrict__ pos_h,
    const int* __restrict__ lab_hv, const int* __restrict__ pos_hv,
    const int* __restrict__ pep,
    float* __restrict__ feat_h,
    float* __restrict__ x, float* __restrict__ x0h,
    int* __restrict__ erow, int* __restrict__ ecol,
    float* __restrict__ emk, float* __restrict__ ebd,
    float* __restrict__ hiW1, float* __restrict__ hjW1,
    float* __restrict__ agg0,
    unsigned short* __restrict__ Wp)
{
    int blk = blockIdx.x, t = threadIdx.x;
    if (blk < HV_BLKS_) {
        int g = blk*256 + t;                 // [0, 409600)
        int l = g / 204800;
        int r = g - l*204800;
        int node = r >> 7, col = r & 127;    // node = b*NH + nh
        int b = node / NH_;
        int label = lab_hv[node], pos = pos_hv[node];
        int aa = pep[b*15 + pos - 1];
        const float* W1l = W1 + l*EDIM_*HID_;
        float hj = W1l[(FDIM_ + label)*HID_ + col]
                 + W1l[(FDIM_ + 44 + aa)*HID_ + col]
                 + W1l[(FDIM_ + 64 + pos - 1)*HID_ + col];
        hjW1[(size_t)(1600 + l*1600 + node)*HID_ + col] = hj;
        return;
    }
    blk -= HV_BLKS_;
    if (blk < PACK_BLKS_) {
        int g = blk*256 + t;
        int idx = g & 16383;
        int lm  = g >> 14;
        int l = lm >> 1, mat = lm & 1;
        int j = idx & 7, q = (idx >> 3) & 3, n = (idx >> 5) & 127, kc = idx >> 12;
        int k = kc*32 + q*8 + j;
        const float* W = (mat == 0 ? W2 : Wc1) + l*HID_*HID_;
        Wp[g] = f2bf(W[k*HID_ + n]);
        return;
    }
    blk -= PACK_BLKS_;
    if (blk < EDGE_BLKS_) {
        int g = blk*256 + t;                  // [0, 83200)
        int b = g / NE_, e = g % NE_;
        if (e < EHH_) return;                 // hh edges handled by sort phase
        int k = e - EHH_;
        int r = k / NH_; int cc = k % NH_; int c = H_ + cc;
        erow[g] = r; ecol[g] = c;
        emk[g] = em_hv[(b*H_ + r)*NH_ + cc];
        ebd[g] = bond [(b*H_ + r)*NH_ + cc];
        return;
    }
    blk -= EDGE_BLKS_;
    if (blk < SORT_BLKS_) {
        // counting-sort the 400 hh edges of batch b by row -> long runs for agg
        int b = blk;
        __shared__ int scnt[64];
        __shared__ int srow[EHH_], scol[EHH_];
        __shared__ float sem[EHH_];
        if (t < 64) scnt[t] = 0;
        __syncthreads();
        for (int e = t; e < EHH_; e += 256) {
            int r = ehh[(b*EHH_ + e)*2 + 0];
            srow[e] = r;
            scol[e] = ehh[(b*EHH_ + e)*2 + 1];
            sem[e]  = em_hh[b*EHH_ + e];
            atomicAdd(&scnt[r], 1);
        }
        __syncthreads();
        if (t == 0) {
            int acc = 0;
            for (int i = 0; i < H_; ++i) { int v = scnt[i]; scnt[i] = acc; acc += v; }
        }
        __syncthreads();
        for (int e = t; e < EHH_; e += 256) {
            int r = srow[e];
            int pos = atomicAdd(&scnt[r], 1);
            int g = b*NE_ + pos;
            erow[g] = r; ecol[g] = scol[e]; emk[g] = sem[e]; ebd[g] = 0.0f;
        }
        return;
    }
    blk -= SORT_BLKS_;
    if (blk < HROW_BLKS_) {
        // h-node layer-0 projections; fold b1 and t*w160 into hiW1
        int g = blk*256 + t;                 // [0, 51200)
        int node = g >> 7, col = g & 127;    // node = b*H + h
        int b = node / H_;
        int label = lab_h[node], pos = pos_h[node];
        int aa = pep[b*15 + pos - 1];
        const float* W1l = W1;               // layer 0
        float hi = W1l[label*HID_ + col]
                 + W1l[(44 + aa)*HID_ + col]
                 + W1l[(64 + pos - 1)*HID_ + col]
                 + b1[col]
                 + t_in[b] * W1l[160*HID_ + col];
        float hj = W1l[(FDIM_ + label)*HID_ + col]
                 + W1l[(FDIM_ + 44 + aa)*HID_ + col]
                 + W1l[(FDIM_ + 64 + pos - 1)*HID_ + col];
        int h = node % H_;
        #pragma unroll
        for (int s = 0; s < S_; ++s) {
            int row = (b*S_ + s)*H_ + h;
            hiW1[(size_t)row*HID_ + col] = hi;
            hjW1[(size_t)row*HID_ + col] = hj;
        }
        return;
    }
    blk -= HROW_BLKS_;
    if (blk < FEAT_BLKS_) {
        int g = blk*256 + t;                 // [0, 32000)
        int node = g / FS_, f = g % FS_;     // node = b*H + h
        int b = node / H_, h = node % H_;
        int label = lab_h[node], pos = pos_h[node];
        int aa = pep[b*15 + pos - 1];
        float v = 0.f;
        if (f < 44)      v = (f == label)          ? 1.0f : 0.0f;
        else if (f < 64) v = ((f - 44) == aa)      ? 1.0f : 0.0f;
        else if (f < 79) v = ((f - 64) == pos - 1) ? 1.0f : 0.0f;
        #pragma unroll
        for (int s = 0; s < S_; ++s)
            feat_h[((b*S_ + s)*H_ + h)*FS_ + f] = v;
        return;
    }
    blk -= FEAT_BLKS_;
    if (blk < ZERO_BLKS_) {
        int idx = blk*256 + t;
        if (idx < 52800) ((float4*)agg0)[idx] = make_float4(0.f, 0.f, 0.f, 0.f);
        return;
    }
    blk -= ZERO_BLKS_;
    {
        int g = blk*256 + t;
        if (g >= BS_*NN_) return;
        int bs = g / NN_, n = g % NN_;
        int b = bs / S_;
        if (n < H_) {
            int ba = bound[b*H_ + n];
            for (int d = 0; d < 3; ++d) {
                float v = x_h[(bs*H_ + n)*3 + d] + x_hv[(b*NH_ + ba)*3 + d];
                x[g*4 + d] = v;
                x0h[(bs*H_ + n)*4 + d] = v;
            }
        } else {
            int nh = n - H_;
            for (int d = 0; d < 3; ++d) x[g*4 + d] = x_hv[(b*NH_ + nh)*3 + d];
        }
    }
}

// ============ per-layer: fused MFMA edge MLP + segment aggregation ============
// (256,4): R10 proved (256,6) forces VGPR 56->40 with scratch spills.
// partT layout: R11 proved the shfl-xor tree costs +8 VGPR and +4 us.
// This is the measured optimum (132.2 us @ R9).
__global__ __launch_bounds__(256, 4) void k_edge_mlp(
    const float* __restrict__ x, const float* __restrict__ hiW1,
    const float* __restrict__ hjW1,
    const int* __restrict__ erow, const int* __restrict__ ecol,
    const float* __restrict__ emk, const float* __restrict__ ebd,
    const float* __restrict__ W1,
    const float* __restrict__ b2, const float* __restrict__ bc1,
    const float* __restrict__ Wc2,
    const unsigned short* __restrict__ Wp, int l,
    float* __restrict__ aggx, float* __restrict__ aggm)
{
    __shared__ unsigned short s_m[TE_][MSTR_];   // 17408 B
    __shared__ float s_partT[16][68];            // 4352 B
    __shared__ float s_diff[TE_][4];
    __shared__ float s_db  [TE_][2];             // dist, bond
    __shared__ float s_emk [TE_];
    __shared__ int   s_ii  [TE_];                // bs*H + row
    __shared__ int   s_jj  [TE_];                // hjW1 row index

    const int t = threadIdx.x;
    const int lane = t & 63, w = t >> 6;
    const int l15 = lane & 15, q = lane >> 4;

    // ---- setup: per-edge scalars ----
    if (t < TE_) {
        int ge = blockIdx.x*TE_ + t;
        int bs = ge / NE_;
        int e  = ge - bs*NE_;
        int b  = bs / S_;
        int row = erow[b*NE_ + e], col = ecol[b*NE_ + e];
        s_ii[t] = bs*H_ + row;
        s_jj[t] = (col < H_) ? (bs*H_ + col) : (1600 + l*1600 + b*NH_ + (col - H_));
        float dx0 = x[(bs*NN_ + row)*4 + 0] - x[(bs*NN_ + col)*4 + 0];
        float dx1 = x[(bs*NN_ + row)*4 + 1] - x[(bs*NN_ + col)*4 + 1];
        float dx2 = x[(bs*NN_ + row)*4 + 2] - x[(bs*NN_ + col)*4 + 2];
        s_diff[t][0] = dx0; s_diff[t][1] = dx1; s_diff[t][2] = dx2;
        s_db[t][0] = sqrtf(dx0*dx0 + dx1*dx1 + dx2*dx2);
        s_db[t][1] = ebd[b*NE_ + e];
        s_emk[t]   = emk[b*NE_ + e];
    }
    __syncthreads();

    const int mrow = w*16 + l15;   // this lane's A-row (edge)

    // ---- stage 1 (register-direct): b1,t*w160 pre-folded into hiW1 ----
    short8 afrag[4];
    {
        const float* W1l = W1 + l*EDIM_*HID_;
        int ri = s_ii[mrow], rj = s_jj[mrow];
        float dist = s_db[mrow][0], bond = s_db[mrow][1];
        const float* pi = hiW1 + (size_t)ri*HID_ + q*8;
        const float* pj = hjW1 + (size_t)rj*HID_ + q*8;
        #pragma unroll
        for (int kc = 0; kc < 4; ++kc) {
            int k0 = kc*32 + q*8;
            float4 a0 = *(const float4*)(pi + kc*32);
            float4 a1 = *(const float4*)(pi + kc*32 + 4);
            float4 c0 = *(const float4*)(pj + kc*32);
            float4 c1 = *(const float4*)(pj + kc*32 + 4);
            float4 wa0 = *(const float4*)(W1l + 158*HID_ + k0);
            float4 wa1 = *(const float4*)(W1l + 158*HID_ + k0 + 4);
            float4 wb0 = *(const float4*)(W1l + 159*HID_ + k0);
            float4 wb1 = *(const float4*)(W1l + 159*HID_ + k0 + 4);
            short8 fr;
            fr[0] = (short)f2bf(silu_(a0.x + c0.x + dist*wa0.x + bond*wb0.x));
            fr[1] = (short)f2bf(silu_(a0.y + c0.y + dist*wa0.y + bond*wb0.y));
            fr[2] = (short)f2bf(silu_(a0.z + c0.z + dist*wa0.z + bond*wb0.z));
            fr[3] = (short)f2bf(silu_(a0.w + c0.w + dist*wa0.w + bond*wb0.w));
            fr[4] = (short)f2bf(silu_(a1.x + c1.x + dist*wa1.x + bond*wb1.x));
            fr[5] = (short)f2bf(silu_(a1.y + c1.y + dist*wa1.y + bond*wb1.y));
            fr[6] = (short)f2bf(silu_(a1.z + c1.z + dist*wa1.z + bond*wb1.z));
            fr[7] = (short)f2bf(silu_(a1.w + c1.w + dist*wa1.w + bond*wb1.w));
            afrag[kc] = fr;
        }
    }

    // ---- stage 2: m = silu(m1 @ W2 + b2) * emask  (bias in acc init) ----
    {
        const unsigned short* Wp2 = Wp + (size_t)(l*2 + 0)*16384;
        const float* b2l = b2 + l*HID_;
        float em4[4];
        #pragma unroll
        for (int r = 0; r < 4; ++r) em4[r] = s_emk[w*16 + q*4 + r];
        #pragma unroll
        for (int nt = 0; nt < 8; ++nt) {
            int colj = nt*16 + l15;
            float bias = b2l[colj];
            f32x4 c = {bias, bias, bias, bias};
            #pragma unroll
            for (int kc = 0; kc < 4; ++kc) {
                short8 bfrag = *(const short8*)&Wp2[((kc*128 + nt*16 + l15)*4 + q)*8];
                c = __builtin_amdgcn_mfma_f32_16x16x32_bf16(afrag[kc], bfrag, c, 0, 0, 0);
            }
            #pragma unroll
            for (int r = 0; r < 4; ++r)
                s_m[w*16 + q*4 + r][colj] = f2bf(silu_(c[r]) * em4[r]);
        }
    }
    __builtin_amdgcn_wave_barrier();   // wave-private rows: ds_write before ds_read

    // ---- stage 3: cw = silu(m @ Wc1 + bc1) @ Wc2 ----
    {
        short8 af2[4];
        #pragma unroll
        for (int kc = 0; kc < 4; ++kc)
            af2[kc] = *(const short8*)&s_m[mrow][kc*32 + q*8];
        const unsigned short* Wp3 = Wp + (size_t)(l*2 + 1)*16384;
        const float* bc1l = bc1 + l*HID_;
        const float* wc2l = Wc2 + l*HID_;
        float p[4] = {0.f, 0.f, 0.f, 0.f};
        #pragma unroll
        for (int nt = 0; nt < 8; ++nt) {
            int colj = nt*16 + l15;
            float bias = bc1l[colj];
            f32x4 c = {bias, bias, bias, bias};
            #pragma unroll
            for (int kc = 0; kc < 4; ++kc) {
                short8 bfrag = *(const short8*)&Wp3[((kc*128 + nt*16 + l15)*4 + q)*8];
                c = __builtin_amdgcn_mfma_f32_16x16x32_bf16(af2[kc], bfrag, c, 0, 0, 0);
            }
            float wcv = wc2l[colj];
            #pragma unroll
            for (int r = 0; r < 4; ++r)
                p[r] += silu_(c[r]) * wcv;
        }
        *(float4*)&s_partT[l15][w*16 + q*4] = make_float4(p[0], p[1], p[2], p[3]);
    }
    __syncthreads();

    // ---- aggregation: wave 0 = cw reduce + aggx via shuffle; waves 1,2 = aggm ----
    if (t < TE_) {
        float cwv = 0.f;
        #pragma unroll
        for (int c = 0; c < 16; ++c) cwv += s_partT[c][t];
        float run = 0.f; int ct = s_ii[0];
        int d = lane & 3;                       // lanes 0..2 meaningful
        for (int i2 = 0; i2 < TE_; ++i2) {
            float cwi = __shfl(cwv, i2, 64);
            int tg = s_ii[i2];
            if (tg != ct) {
                if (lane < 3) atomicAdd(&aggx[(size_t)ct*4 + d], run);
                run = 0.f; ct = tg;
            }
            run += s_diff[i2][d] * cwi;
        }
        if (lane < 3) atomicAdd(&aggx[(size_t)ct*4 + d], run);
    } else if (t < TE_ + HID_) {
        int j = t - TE_;
        float run = 0.f; int ct = s_ii[0];
        for (int i2 = 0; i2 < TE_; ++i2) {
            int tg = s_ii[i2];
            if (tg != ct) {
                atomicAdd(&aggm[(size_t)ct*HID_ + j], run);
                run = 0.f; ct = tg;
            }
            run += bf2f(s_m[i2][j]);
        }
        atomicAdd(&aggm[(size_t)ct*HID_ + j], run);
    }
}

// ====== per-layer: node update (8 nodes/block) + next-layer W1 (folded) + out ======
__global__ __launch_bounds__(128) void k_update(
    float* __restrict__ feat_h, float* __restrict__ x,
    const float* __restrict__ aggm, const float* __restrict__ aggx,
    const float* __restrict__ Wn1, const float* __restrict__ bn1,
    const float* __restrict__ Wn2, const float* __restrict__ bn2, int l,
    const float* __restrict__ W1, const float* __restrict__ b1,
    const float* __restrict__ t_in,
    float* __restrict__ hiW1, float* __restrict__ hjW1,
    float* __restrict__ zbase, int do_w1,
    const float* __restrict__ x0h, const float* __restrict__ amask,
    float* __restrict__ out)
{
    if (blockIdx.x >= 200) {
        int z = blockIdx.x - 200;
        for (int idx = z*128 + threadIdx.x; idx < 52800; idx += 207*128)
            ((float4*)zbase)[idx] = make_float4(0.f, 0.f, 0.f, 0.f);
        return;
    }
    __shared__ float s_in[8][NDIM_ + 1];
    __shared__ float s_u[8][HID_ + 1];
    int node0 = blockIdx.x * 8;            // bs*H + h
    int t = threadIdx.x;
    for (int idx = t; idx < 8*(NDIM_ + 1); idx += 128) {
        int g = idx / (NDIM_ + 1), k = idx % (NDIM_ + 1);
        float v = 0.f;
        if (k < FDIM_)      v = feat_h[(node0 + g)*FS_ + k];
        else if (k < NDIM_) v = aggm[(size_t)(node0 + g)*HID_ + (k - FDIM_)];
        s_in[g][k] = v;
    }
    __syncthreads();
    const float* Wn1l = Wn1 + l*NDIM_*HID_;
    float acc[8];
    float bv = bn1[l*HID_ + t];
    #pragma unroll
    for (int g = 0; g < 8; ++g) acc[g] = bv;
    for (int k = 0; k < NDIM_; ++k) {
        float wv = Wn1l[k*HID_ + t];
        #pragma unroll
        for (int g = 0; g < 8; ++g) acc[g] += s_in[g][k] * wv;
    }
    #pragma unroll
    for (int g = 0; g < 8; ++g) s_u[g][t] = silu_(acc[g]);
    __syncthreads();
    if (t < FDIM_) {
        const float* Wn2l = Wn2 + l*HID_*FDIM_;
        float acc2[8];
        float b2v = bn2[l*FDIM_ + t];
        #pragma unroll
        for (int g = 0; g < 8; ++g) acc2[g] = b2v;
        for (int k = 0; k < HID_; ++k) {
            float wv = Wn2l[k*FDIM_ + t];
            #pragma unroll
            for (int g = 0; g < 8; ++g) acc2[g] += s_u[g][k] * wv;
        }
        #pragma unroll
        for (int g = 0; g < 8; ++g) {
            float nf = s_in[g][t] + acc2[g];
            feat_h[(node0 + g)*FS_ + t] = nf;
            s_in[g][t] = nf;
        }
    } else if (t >= 96 && t < 120) {
        int idx = t - 96, g = idx / 3, d = idx % 3;
        int node = node0 + g;
        int bs = node / H_, h = node % H_;
        float xv = x[(bs*NN_ + h)*4 + d] + aggx[node*4 + d];
        x[(bs*NN_ + h)*4 + d] = xv;
        if (!do_w1) {
            int b = bs / S_;
            out[node*3 + d] = (xv - x0h[node*4 + d]) * amask[b*H_ + h];
        }
    }
    if (!do_w1) return;
    __syncthreads();
    // ---- next-layer W1 projections (fold b1 + t*w160 into hiW1) ----
    {
        const float* W1n = W1 + (l + 1)*EDIM_*HID_;
        float w160 = W1n[160*HID_ + t];
        float b1v  = b1[(l + 1)*HID_ + t];
        float hia[8], hja[8];
        #pragma unroll
        for (int g = 0; g < 8; ++g) { hia[g] = 0.f; hja[g] = 0.f; }
        for (int f = 0; f < FDIM_; ++f) {
            float wi = W1n[f*HID_ + t];
            float wj = W1n[(FDIM_ + f)*HID_ + t];
            #pragma unroll
            for (int g = 0; g < 8; ++g) {
                float v = s_in[g][f];
                hia[g] += v * wi;
                hja[g] += v * wj;
            }
        }
        #pragma unroll
        for (int g = 0; g < 8; ++g) {
            int node = node0 + g;
            int b = (node / H_) / S_;
            hiW1[(size_t)node*HID_ + t] = hia[g] + b1v + t_in[b]*w160;
            hjW1[(size_t)node*HID_ + t] = hja[g];
        }
    }
}

// ---------------- launch ----------------
extern "C" void kernel_launch(void* const* d_in, const int* in_sizes, int n_in,
                              void* d_out, int out_size, void* d_ws, size_t ws_size,
                              hipStream_t stream)
{
    const float* t_in  = (const float*)d_in[0];
    const float* x_h   = (const float*)d_in[1];
    const float* x_hv  = (const float*)d_in[2];
    const float* bond  = (const float*)d_in[3];
    const float* em_hv = (const float*)d_in[4];
    const float* em_hh = (const float*)d_in[5];
    const float* amask = (const float*)d_in[6];
    const float* W1    = (const float*)d_in[7];
    const float* b1    = (const float*)d_in[8];
    const float* W2    = (const float*)d_in[9];
    const float* b2    = (const float*)d_in[10];
    const float* Wc1   = (const float*)d_in[11];
    const float* bc1   = (const float*)d_in[12];
    const float* Wc2   = (const float*)d_in[13];
    const float* Wn1   = (const float*)d_in[14];
    const float* bn1   = (const float*)d_in[15];
    const float* Wn2   = (const float*)d_in[16];
    const float* bn2   = (const float*)d_in[17];
    const int* pep     = (const int*)d_in[18];
    const int* lab_hv  = (const int*)d_in[19];
    const int* lab_h   = (const int*)d_in[20];
    const int* pos_hv  = (const int*)d_in[21];
    const int* pos_h   = (const int*)d_in[22];
    const int* ehh     = (const int*)d_in[23];
    const int* bound   = (const int*)d_in[24];

    float* ws     = (float*)d_ws;
    float* feat_h = ws + OFF_FEATH;
    float* x      = ws + OFF_X;
    float* x0h    = ws + OFF_X0H;
    int*   erow   = (int*)(ws + OFF_EROW);
    int*   ecol   = (int*)(ws + OFF_ECOL);
    float* emk    = ws + OFF_EMASK;
    float* ebd    = ws + OFF_EBOND;
    float* hiW1   = ws + OFF_HIW1;
    float* hjW1   = ws + OFF_HJW1;
    unsigned short* Wp = (unsigned short*)(ws + OFF_WP);

    hipLaunchKernelGGL(k_setup, dim3(SETUP_BLKS_), dim3(256), 0, stream,
                       x_h, x_hv, bound, ehh, em_hh, em_hv, bond,
                       W1, b1, t_in, W2, Wc1,
                       lab_h, pos_h, lab_hv, pos_hv, pep,
                       feat_h, x, x0h, erow, ecol, emk, ebd,
                       hiW1, hjW1, ws + OFF_AGG0, Wp);

    for (int l = 0; l < L_; ++l) {
        float* aggx_l = ws + OFF_AGG0 + (size_t)l*AGGSTRIDE_;
        float* aggm_l = aggx_l + 6400;
        hipLaunchKernelGGL(k_edge_mlp, dim3(TOTE_/TE_), dim3(256), 0, stream,
                           x, hiW1, hjW1, erow, ecol, emk, ebd,
                           W1, b2, bc1, Wc2, Wp, l, aggx_l, aggm_l);
        int do_w1 = (l == 0);
        float* zbase = ws + OFF_AGG0 + (size_t)(l + 1)*AGGSTRIDE_;
        hipLaunchKernelGGL(k_update, dim3(do_w1 ? 407 : 200), dim3(128), 0, stream,
                           feat_h, x, aggm_l, aggx_l, Wn1, bn1, Wn2, bn2, l,
                           W1, b1, t_in, hiW1, hjW1,
                           do_w1 ? zbase : (ws + OFF_AGG0), do_w1,
                           x0h, amask, (float*)d_out);
    }
}